// Round 20
// baseline (221.902 us; speedup 1.0000x reference)
//
#include <hip/hip_runtime.h>
#include <math.h>

// Shapes (fixed by the problem)
#define NB 2
#define NS 2048
#define ND 1024
#define NH 16
#define NHD 64

typedef __bf16 bf16;
typedef __attribute__((ext_vector_type(2))) __bf16 bf16x2;
typedef __attribute__((ext_vector_type(4))) __bf16 bf16x4;
typedef __attribute__((ext_vector_type(8))) __bf16 bf16x8;
typedef __attribute__((ext_vector_type(4))) float f32x4;
typedef __attribute__((ext_vector_type(16))) float f32x16;
typedef unsigned int u32;
typedef __attribute__((ext_vector_type(2))) unsigned int u32x2;
typedef __attribute__((ext_vector_type(4))) unsigned int u32x4;

__device__ __forceinline__ float bf2f(bf16 x) {
    unsigned int w = ((unsigned int)__builtin_bit_cast(unsigned short, x)) << 16;
    return __builtin_bit_cast(float, w);
}
__device__ __forceinline__ bf16 f2bf(float f) { return (bf16)f; }
__device__ __forceinline__ u32 pack2bf(float a, float b) {
    bf16x2 t = { (bf16)a, (bf16)b };
    return __builtin_bit_cast(u32, t);
}

__device__ __forceinline__ f32x4 mfma16(bf16x8 a, bf16x8 b, f32x4 c) {
    return __builtin_amdgcn_mfma_f32_16x16x32_bf16(a, b, c, 0, 0, 0);
}
__device__ __forceinline__ f32x16 mfma32(bf16x8 a, bf16x8 b, f32x16 c) {
    return __builtin_amdgcn_mfma_f32_32x32x16_bf16(a, b, c, 0, 0, 0);
}

__global__ void write_marker_f(float* out, float v) { out[0] = v; }

// fp32 -> bf16 bulk convert, 8 elems/thread, 16B stores. n8 = n/8.
__global__ __launch_bounds__(256) void cvt_f32_bf16(
    const float* __restrict__ src, bf16* __restrict__ dst, int n8)
{
    const int i = blockIdx.x * 256 + threadIdx.x;
    if (i >= n8) return;
    const f32x4* s4 = reinterpret_cast<const f32x4*>(src) + 2 * (size_t)i;
    f32x4 a = s4[0], b = s4[1];
    u32x4 p = { pack2bf(a[0], a[1]), pack2bf(a[2], a[3]),
                pack2bf(b[0], b[1]), pack2bf(b[2], b[3]) };
    *reinterpret_cast<u32x4*>(dst + 8 * (size_t)i) = p;
}

// Pure-bf16 GEMM: C = A @ W^T + bias, bf16 out. 128x64 tile, BK=32,
// global_load_lds(16B) staging (m97 pattern). (unchanged from r19)
__global__ __launch_bounds__(256) void gemm_bb(
    const bf16* __restrict__ A, const bf16* __restrict__ W,
    const float* __restrict__ bias, bf16* __restrict__ C,
    int M, int N, int K)
{
    constexpr int BK = 32;
    __shared__ bf16 At[128 * BK];
    __shared__ bf16 Bt[64 * BK];

    const int tid   = threadIdx.x;
    const int lane  = tid & 63;
    const int wave  = tid >> 6;
    const int row16 = lane & 15;
    const int grp   = lane >> 4;
    const int m0 = blockIdx.x * 128;
    const int n0 = blockIdx.y * 64;
    const int wr = (wave >> 1) * 64;
    const int wc = (wave & 1) * 32;

    f32x4 acc[4][2] = {};

    const int cA0 = wave * 64 + lane;
    const int cA1 = cA0 + 256;
    const int rA0 = cA0 >> 2, kA0 = (cA0 & 3) * 8;
    const int rA1 = cA1 >> 2, kA1 = (cA1 & 3) * 8;
    const int rB  = cA0 >> 2, kB  = (cA0 & 3) * 8;

    for (int k0 = 0; k0 < K; k0 += BK) {
        __builtin_amdgcn_global_load_lds(
            (const __attribute__((address_space(1))) void*)(A + (size_t)(m0 + rA0) * K + k0 + kA0),
            (__attribute__((address_space(3))) void*)(At + wave * 512), 16, 0, 0);
        __builtin_amdgcn_global_load_lds(
            (const __attribute__((address_space(1))) void*)(A + (size_t)(m0 + rA1) * K + k0 + kA1),
            (__attribute__((address_space(3))) void*)(At + 2048 + wave * 512), 16, 0, 0);
        __builtin_amdgcn_global_load_lds(
            (const __attribute__((address_space(1))) void*)(W + (size_t)(n0 + rB) * K + k0 + kB),
            (__attribute__((address_space(3))) void*)(Bt + wave * 512), 16, 0, 0);
        __syncthreads();

        bf16x8 a[4], b[2];
        #pragma unroll
        for (int i = 0; i < 4; ++i)
            a[i] = *reinterpret_cast<const bf16x8*>(At + (wr + i * 16 + row16) * BK + grp * 8);
        #pragma unroll
        for (int j = 0; j < 2; ++j)
            b[j] = *reinterpret_cast<const bf16x8*>(Bt + (wc + j * 16 + row16) * BK + grp * 8);
        #pragma unroll
        for (int i = 0; i < 4; ++i)
            #pragma unroll
            for (int j = 0; j < 2; ++j)
                acc[i][j] = mfma16(a[i], b[j], acc[i][j]);
        __syncthreads();
    }

    #pragma unroll
    for (int j = 0; j < 2; ++j) {
        const int n = n0 + wc + j * 16 + row16;
        const float bv = bias[n];
        #pragma unroll
        for (int i = 0; i < 4; ++i) {
            #pragma unroll
            for (int r = 0; r < 4; ++r) {
                const int m = m0 + wr + i * 16 + grp * 4 + r;
                C[(size_t)m * N + n] = f2bf(acc[i][j][r] + bv);
            }
        }
    }
}

// Same but fp32 output (final projection).
__global__ __launch_bounds__(256) void gemm_bb_f32(
    const bf16* __restrict__ A, const bf16* __restrict__ W,
    const float* __restrict__ bias, float* __restrict__ C,
    int M, int N, int K)
{
    constexpr int BK = 32;
    __shared__ bf16 At[128 * BK];
    __shared__ bf16 Bt[64 * BK];

    const int tid   = threadIdx.x;
    const int lane  = tid & 63;
    const int wave  = tid >> 6;
    const int row16 = lane & 15;
    const int grp   = lane >> 4;
    const int m0 = blockIdx.x * 128;
    const int n0 = blockIdx.y * 64;
    const int wr = (wave >> 1) * 64;
    const int wc = (wave & 1) * 32;

    f32x4 acc[4][2] = {};

    const int cA0 = wave * 64 + lane;
    const int cA1 = cA0 + 256;
    const int rA0 = cA0 >> 2, kA0 = (cA0 & 3) * 8;
    const int rA1 = cA1 >> 2, kA1 = (cA1 & 3) * 8;
    const int rB  = cA0 >> 2, kB  = (cA0 & 3) * 8;

    for (int k0 = 0; k0 < K; k0 += BK) {
        __builtin_amdgcn_global_load_lds(
            (const __attribute__((address_space(1))) void*)(A + (size_t)(m0 + rA0) * K + k0 + kA0),
            (__attribute__((address_space(3))) void*)(At + wave * 512), 16, 0, 0);
        __builtin_amdgcn_global_load_lds(
            (const __attribute__((address_space(1))) void*)(A + (size_t)(m0 + rA1) * K + k0 + kA1),
            (__attribute__((address_space(3))) void*)(At + 2048 + wave * 512), 16, 0, 0);
        __builtin_amdgcn_global_load_lds(
            (const __attribute__((address_space(1))) void*)(W + (size_t)(n0 + rB) * K + k0 + kB),
            (__attribute__((address_space(3))) void*)(Bt + wave * 512), 16, 0, 0);
        __syncthreads();

        bf16x8 a[4], b[2];
        #pragma unroll
        for (int i = 0; i < 4; ++i)
            a[i] = *reinterpret_cast<const bf16x8*>(At + (wr + i * 16 + row16) * BK + grp * 8);
        #pragma unroll
        for (int j = 0; j < 2; ++j)
            b[j] = *reinterpret_cast<const bf16x8*>(Bt + (wc + j * 16 + row16) * BK + grp * 8);
        #pragma unroll
        for (int i = 0; i < 4; ++i)
            #pragma unroll
            for (int j = 0; j < 2; ++j)
                acc[i][j] = mfma16(a[i], b[j], acc[i][j]);
        __syncthreads();
    }

    #pragma unroll
    for (int j = 0; j < 2; ++j) {
        const int n = n0 + wc + j * 16 + row16;
        const float bv = bias[n];
        #pragma unroll
        for (int i = 0; i < 4; ++i) {
            #pragma unroll
            for (int r = 0; r < 4; ++r) {
                const int m = m0 + wr + i * 16 + grp * 4 + r;
                C[(size_t)m * N + n] = acc[i][j][r] + bv;
            }
        }
    }
}

// Mixed GEMM (V-proj): A fp32 (reg-staged + native cvt), W bf16 (gload_lds).
__global__ __launch_bounds__(256) void gemm_fb(
    const float* __restrict__ A, const bf16* __restrict__ W,
    const float* __restrict__ bias, bf16* __restrict__ C,
    int M, int N, int K)
{
    constexpr int BK = 32;
    __shared__ bf16 At[128 * BK];
    __shared__ bf16 Bt[64 * BK];

    const int tid   = threadIdx.x;
    const int lane  = tid & 63;
    const int wave  = tid >> 6;
    const int row16 = lane & 15;
    const int grp   = lane >> 4;
    const int m0 = blockIdx.x * 128;
    const int n0 = blockIdx.y * 64;
    const int wr = (wave >> 1) * 64;
    const int wc = (wave & 1) * 32;

    f32x4 acc[4][2] = {};

    const int cB = wave * 64 + lane;
    const int rB = cB >> 2, kB = (cB & 3) * 8;

    for (int k0 = 0; k0 < K; k0 += BK) {
        __builtin_amdgcn_global_load_lds(
            (const __attribute__((address_space(1))) void*)(W + (size_t)(n0 + rB) * K + k0 + kB),
            (__attribute__((address_space(3))) void*)(Bt + wave * 512), 16, 0, 0);
        #pragma unroll
        for (int i = 0; i < 4; ++i) {
            const int c   = tid + 256 * i;
            const int r   = c >> 3;
            const int col = (c & 7) * 4;
            f32x4 va = *reinterpret_cast<const f32x4*>(A + (size_t)(m0 + r) * K + k0 + col);
            u32x2 pa = { pack2bf(va[0], va[1]), pack2bf(va[2], va[3]) };
            *reinterpret_cast<u32x2*>(At + r * BK + col) = pa;
        }
        __syncthreads();

        bf16x8 a[4], b[2];
        #pragma unroll
        for (int i = 0; i < 4; ++i)
            a[i] = *reinterpret_cast<const bf16x8*>(At + (wr + i * 16 + row16) * BK + grp * 8);
        #pragma unroll
        for (int j = 0; j < 2; ++j)
            b[j] = *reinterpret_cast<const bf16x8*>(Bt + (wc + j * 16 + row16) * BK + grp * 8);
        #pragma unroll
        for (int i = 0; i < 4; ++i)
            #pragma unroll
            for (int j = 0; j < 2; ++j)
                acc[i][j] = mfma16(a[i], b[j], acc[i][j]);
        __syncthreads();
    }

    #pragma unroll
    for (int j = 0; j < 2; ++j) {
        const int n = n0 + wc + j * 16 + row16;
        const float bv = bias[n];
        #pragma unroll
        for (int i = 0; i < 4; ++i) {
            #pragma unroll
            for (int r = 0; r < 4; ++r) {
                const int m = m0 + wr + i * 16 + grp * 4 + r;
                C[(size_t)m * N + n] = f2bf(acc[i][j][r] + bv);
            }
        }
    }
}

// Flash attention, swapped-QK^T 32x32. r20 changes:
//  - COMBINED softmax over the full 64-k tile (both subtiles' S computed
//    first): one max-chain + one shfl + one rescale pass per tile.
//  - Narrow defer-max guard (THR=8, log2 domain): rescale block only runs
//    when some lane's tile-max exceeds mrow+8 (wave-uniform branch, single
//    exp-loop copy -> no r15-style register blowup). P <= 2^8, safe in bf16.
__global__ __launch_bounds__(256) void attn_fwd(
    const bf16* __restrict__ Q, const bf16* __restrict__ K,
    const bf16* __restrict__ V, bf16* __restrict__ Y)
{
    constexpr int LDK = 72;
    constexpr int LDV = 72;
    constexpr int LDP = 40;
    __shared__ bf16 Kt[64 * LDK];
    __shared__ bf16 Vt[64 * LDV];
    __shared__ bf16 Pt[4 * 32 * LDP];

    const int tid  = threadIdx.x;
    const int lane = tid & 63;
    const int wave = tid >> 6;
    const int l31  = lane & 31;
    const int hi   = lane >> 5;
    const int bh = blockIdx.y;
    const size_t base = (size_t)(bh >> 4) * NS * ND + (size_t)(bh & 15) * NHD;
    const int q0 = blockIdx.x * 128 + wave * 32;

    const float qscale = 0.125f * 1.44269504f;
    bf16x8 qB[4];
    {
        const bf16* qp = Q + base + (size_t)(q0 + l31) * ND + hi * 8;
        #pragma unroll
        for (int c = 0; c < 4; ++c) {
            bf16x8 t = *reinterpret_cast<const bf16x8*>(qp + c * 16);
            #pragma unroll
            for (int j = 0; j < 8; ++j) qB[c][j] = f2bf(bf2f(t[j]) * qscale);
        }
    }

    float mrow = -INFINITY, lrow = 0.f;
    f32x16 yacc0 = {}, yacc1 = {};

    const int a8  = tid & 7;
    const int rk  = tid >> 3;
    const int e0  = a8 * 8;
    const int rp  = tid >> 3;
    const int d0  = a8 * 8;

    bf16* const ptW = Pt + wave * 32 * LDP;

    for (int k0 = 0; k0 < NS; k0 += 64) {
        __syncthreads();
        #pragma unroll
        for (int h = 0; h < 2; ++h) {
            const int r = rk + h * 32;
            *reinterpret_cast<bf16x8*>(Kt + r * LDK + e0) =
                *reinterpret_cast<const bf16x8*>(K + base + (size_t)(k0 + r) * ND + e0);
        }
        {
            const bf16* vp = V + base + (size_t)(k0 + 2 * rp) * ND + d0;
            bf16x8 v0 = *reinterpret_cast<const bf16x8*>(vp);
            bf16x8 v1 = *reinterpret_cast<const bf16x8*>(vp + ND);
            #pragma unroll
            for (int j = 0; j < 8; ++j) {
                const int jj = (j + a8) & 7;
                bf16x2 pr = { v0[jj], v1[jj] };
                *reinterpret_cast<u32*>(Vt + (d0 + jj) * LDV + 2 * rp) =
                    __builtin_bit_cast(u32, pr);
            }
        }
        __syncthreads();

        // ---- S for BOTH subtiles ----
        f32x16 s0 = {}, s1 = {};
        #pragma unroll
        for (int c = 0; c < 4; ++c) {
            bf16x8 kf = *reinterpret_cast<const bf16x8*>(
                Kt + l31 * LDK + c * 16 + hi * 8);
            s0 = mfma32(kf, qB[c], s0);
        }
        #pragma unroll
        for (int c = 0; c < 4; ++c) {
            bf16x8 kf = *reinterpret_cast<const bf16x8*>(
                Kt + (32 + l31) * LDK + c * 16 + hi * 8);
            s1 = mfma32(kf, qB[c], s1);
        }

        // ---- combined softmax over 64 k (lane holds 32, partner holds 32) ----
        float rmax = s0[0];
        #pragma unroll
        for (int i = 1; i < 16; ++i) rmax = fmaxf(rmax, s0[i]);
        #pragma unroll
        for (int i = 0; i < 16; ++i) rmax = fmaxf(rmax, s1[i]);
        rmax = fmaxf(rmax, __shfl_xor(rmax, 32));
        if (!__all(rmax <= mrow + 8.0f)) {       // defer-max: rare rescale
            const float mnew = fmaxf(mrow, rmax);
            const float corr = exp2f(mrow - mnew);   // first tile: 0
            lrow *= corr;
            #pragma unroll
            for (int i = 0; i < 16; ++i) { yacc0[i] *= corr; yacc1[i] *= corr; }
            mrow = mnew;
        }
        float psum = 0.f;
        #pragma unroll
        for (int i = 0; i < 16; ++i) { s0[i] = exp2f(s0[i] - mrow); psum += s0[i]; }
        #pragma unroll
        for (int i = 0; i < 16; ++i) { s1[i] = exp2f(s1[i] - mrow); psum += s1[i]; }
        lrow += psum;

        // ---- subtile 0: P -> LDS, PV ----
        #pragma unroll
        for (int cp = 0; cp < 4; ++cp) {
            u32x2 pw = { pack2bf(s0[4 * cp + 0], s0[4 * cp + 1]),
                         pack2bf(s0[4 * cp + 2], s0[4 * cp + 3]) };
            *reinterpret_cast<u32x2*>(ptW + l31 * LDP + 8 * cp + 4 * hi) = pw;
        }
        #pragma unroll
        for (int kc = 0; kc < 2; ++kc) {
            bf16x8 pf = *reinterpret_cast<const bf16x8*>(
                ptW + l31 * LDP + kc * 16 + hi * 8);
            bf16x8 vf0 = *reinterpret_cast<const bf16x8*>(
                Vt + l31 * LDV + kc * 16 + hi * 8);
            bf16x8 vf1 = *reinterpret_cast<const bf16x8*>(
                Vt + (32 + l31) * LDV + kc * 16 + hi * 8);
            yacc0 = mfma32(vf0, pf, yacc0);
            yacc1 = mfma32(vf1, pf, yacc1);
        }
        // ---- subtile 1: P -> LDS, PV (same-wave DS ordering is in-order) ----
        #pragma unroll
        for (int cp = 0; cp < 4; ++cp) {
            u32x2 pw = { pack2bf(s1[4 * cp + 0], s1[4 * cp + 1]),
                         pack2bf(s1[4 * cp + 2], s1[4 * cp + 3]) };
            *reinterpret_cast<u32x2*>(ptW + l31 * LDP + 8 * cp + 4 * hi) = pw;
        }
        #pragma unroll
        for (int kc = 0; kc < 2; ++kc) {
            bf16x8 pf = *reinterpret_cast<const bf16x8*>(
                ptW + l31 * LDP + kc * 16 + hi * 8);
            bf16x8 vf0 = *reinterpret_cast<const bf16x8*>(
                Vt + l31 * LDV + 32 + kc * 16 + hi * 8);
            bf16x8 vf1 = *reinterpret_cast<const bf16x8*>(
                Vt + (32 + l31) * LDV + 32 + kc * 16 + hi * 8);
            yacc0 = mfma32(vf0, pf, yacc0);
            yacc1 = mfma32(vf1, pf, yacc1);
        }
    }

    lrow += __shfl_xor(lrow, 32);
    const float inv = 1.f / lrow;
    bf16* yp = Y + base + (size_t)(q0 + l31) * ND;
    #pragma unroll
    for (int cp = 0; cp < 4; ++cp) {
        bf16x4 o0 = { f2bf(yacc0[4*cp+0] * inv), f2bf(yacc0[4*cp+1] * inv),
                      f2bf(yacc0[4*cp+2] * inv), f2bf(yacc0[4*cp+3] * inv) };
        bf16x4 o1 = { f2bf(yacc1[4*cp+0] * inv), f2bf(yacc1[4*cp+1] * inv),
                      f2bf(yacc1[4*cp+2] * inv), f2bf(yacc1[4*cp+3] * inv) };
        *reinterpret_cast<bf16x4*>(yp + 8 * cp + 4 * hi)      = o0;
        *reinterpret_cast<bf16x4*>(yp + 32 + 8 * cp + 4 * hi) = o1;
    }
}

extern "C" void kernel_launch(void* const* d_in, const int* in_sizes, int n_in,
                              void* d_out, int out_size, void* d_ws, size_t ws_size,
                              hipStream_t stream) {
    float* outF = (float*)d_out;   // OUTPUT IS FLOAT32

    int c4 = 0, cW = 0, cB = 0;
    for (int i = 0; i < n_in; ++i) {
        if (in_sizes[i] == NB * NS * ND) ++c4;
        else if (in_sizes[i] == ND * ND) ++cW;
        else if (in_sizes[i] == ND) ++cB;
    }
    if (c4 != 3 || cW != 4 || cB != 4) {
        write_marker_f<<<1, 1, 0, stream>>>(outF, 2.0f);
        return;
    }
    const size_t tsz = (size_t)NB * NS * ND;       // 4194304
    if (ws_size < 2 * tsz * sizeof(bf16)) {        // 16 MiB
        write_marker_f<<<1, 1, 0, stream>>>(outF, 1.0f);
        return;
    }

    const float* q  = (const float*)d_in[0];
    const float* k  = (const float*)d_in[1];
    const float* v  = (const float*)d_in[2];
    const float* Wq = (const float*)d_in[4];
    const float* bq = (const float*)d_in[5];
    const float* Wk = (const float*)d_in[6];
    const float* bk = (const float*)d_in[7];
    const float* Wv = (const float*)d_in[8];
    const float* bv = (const float*)d_in[9];
    const float* Wo = (const float*)d_in[10];
    const float* bo = (const float*)d_in[11];

    // Scratch choreography (race-checked, r19):
    //  S0 = ws[0:8MB]   : Qb, then Y (attn in-place, disjoint slices)
    //  S1 = ws[8:16MB]  : Wq|Wk|Wv|Wo bf16 (written once, read-only after)
    //  D0 = d_out[0:8MB]: qbf -> kbf -> Vb (dead before final GEMM)
    //  D1 = d_out[8:16MB]: Kb              (dead before final GEMM)
    bf16* S0 = (bf16*)d_ws;
    bf16* S1 = S0 + tsz;
    bf16* D0 = (bf16*)d_out;
    bf16* D1 = D0 + tsz;
    const size_t wsz = (size_t)ND * ND;

    const int M = NB * NS;
    dim3 gg(M / 128, ND / 64);

    cvt_f32_bf16<<<(int)(wsz / 8 / 256), 256, 0, stream>>>(Wq, S1 + 0 * wsz, (int)(wsz / 8));
    cvt_f32_bf16<<<(int)(wsz / 8 / 256), 256, 0, stream>>>(Wk, S1 + 1 * wsz, (int)(wsz / 8));
    cvt_f32_bf16<<<(int)(wsz / 8 / 256), 256, 0, stream>>>(Wv, S1 + 2 * wsz, (int)(wsz / 8));
    cvt_f32_bf16<<<(int)(wsz / 8 / 256), 256, 0, stream>>>(Wo, S1 + 3 * wsz, (int)(wsz / 8));
    cvt_f32_bf16<<<(int)(tsz / 8 / 256), 256, 0, stream>>>(q, D0, (int)(tsz / 8));
    gemm_bb<<<gg, 256, 0, stream>>>(D0, S1 + 0 * wsz, bq, S0, M, ND, ND);
    cvt_f32_bf16<<<(int)(tsz / 8 / 256), 256, 0, stream>>>(k, D0, (int)(tsz / 8));
    gemm_bb<<<gg, 256, 0, stream>>>(D0, S1 + 1 * wsz, bk, D1, M, ND, ND);
    gemm_fb<<<gg, 256, 0, stream>>>(v, S1 + 2 * wsz, bv, D0, M, ND, ND);
    attn_fwd<<<dim3(NS / 128, NB * NH), 256, 0, stream>>>(S0, D1, D0, S0);
    gemm_bb_f32<<<gg, 256, 0, stream>>>(S0, S1 + 3 * wsz, bo, outF, M, ND, ND);
}

// Round 21
// 183.277 us; speedup vs baseline: 1.2107x; 1.2107x over previous
//
#include <hip/hip_runtime.h>
#include <math.h>

// Shapes (fixed by the problem)
#define NB 2
#define NS 2048
#define ND 1024
#define NH 16
#define NHD 64

typedef __bf16 bf16;
typedef __attribute__((ext_vector_type(2))) __bf16 bf16x2;
typedef __attribute__((ext_vector_type(4))) __bf16 bf16x4;
typedef __attribute__((ext_vector_type(8))) __bf16 bf16x8;
typedef __attribute__((ext_vector_type(4))) float f32x4;
typedef __attribute__((ext_vector_type(16))) float f32x16;
typedef unsigned int u32;
typedef __attribute__((ext_vector_type(2))) unsigned int u32x2;
typedef __attribute__((ext_vector_type(4))) unsigned int u32x4;

__device__ __forceinline__ float bf2f(bf16 x) {
    unsigned int w = ((unsigned int)__builtin_bit_cast(unsigned short, x)) << 16;
    return __builtin_bit_cast(float, w);
}
__device__ __forceinline__ bf16 f2bf(float f) { return (bf16)f; }
__device__ __forceinline__ u32 pack2bf(float a, float b) {
    bf16x2 t = { (bf16)a, (bf16)b };
    return __builtin_bit_cast(u32, t);
}

__device__ __forceinline__ f32x4 mfma16(bf16x8 a, bf16x8 b, f32x4 c) {
    return __builtin_amdgcn_mfma_f32_16x16x32_bf16(a, b, c, 0, 0, 0);
}
__device__ __forceinline__ f32x16 mfma32(bf16x8 a, bf16x8 b, f32x16 c) {
    return __builtin_amdgcn_mfma_f32_32x32x16_bf16(a, b, c, 0, 0, 0);
}

__global__ void write_marker_f(float* out, float v) { out[0] = v; }

// fp32 -> bf16 bulk convert (single tensor).
__global__ __launch_bounds__(256) void cvt_f32_bf16(
    const float* __restrict__ src, bf16* __restrict__ dst, int n8)
{
    const int i = blockIdx.x * 256 + threadIdx.x;
    if (i >= n8) return;
    const f32x4* s4 = reinterpret_cast<const f32x4*>(src) + 2 * (size_t)i;
    f32x4 a = s4[0], b = s4[1];
    u32x4 p = { pack2bf(a[0], a[1]), pack2bf(a[2], a[3]),
                pack2bf(b[0], b[1]), pack2bf(b[2], b[3]) };
    *reinterpret_cast<u32x4*>(dst + 8 * (size_t)i) = p;
}

// Fused 4-tensor fp32 -> bf16 (the four weight matrices -> contiguous dst).
__global__ __launch_bounds__(256) void cvt4_f32_bf16(
    const float* __restrict__ s0, const float* __restrict__ s1,
    const float* __restrict__ s2, const float* __restrict__ s3,
    bf16* __restrict__ dst, int n8each)
{
    const int i = blockIdx.x * 256 + threadIdx.x;
    const int t = i / n8each;            // 0..3 (uniform per block: 256 | n8each)
    const int j = i - t * n8each;
    const float* src = (t == 0) ? s0 : (t == 1) ? s1 : (t == 2) ? s2 : s3;
    const f32x4* s4 = reinterpret_cast<const f32x4*>(src) + 2 * (size_t)j;
    f32x4 a = s4[0], b = s4[1];
    u32x4 p = { pack2bf(a[0], a[1]), pack2bf(a[2], a[3]),
                pack2bf(b[0], b[1]), pack2bf(b[2], b[3]) };
    *reinterpret_cast<u32x4*>(dst + (size_t)t * n8each * 8 + 8 * (size_t)j) = p;
}

// Pure-bf16 GEMM: C = A @ W^T + bias, bf16 out. 128x64 tile, BK=64 staged as
// TWO 32-k LDS halves (same bank geometry as the verified BK=32 layout, half
// the barriers). global_load_lds(16B) staging.
__global__ __launch_bounds__(256) void gemm_bb(
    const bf16* __restrict__ A, const bf16* __restrict__ W,
    const float* __restrict__ bias, bf16* __restrict__ C,
    int M, int N, int K)
{
    __shared__ bf16 At[2 * 128 * 32];   // halves at 0, 4096
    __shared__ bf16 Bt[2 * 64 * 32];    // halves at 0, 2048

    const int tid   = threadIdx.x;
    const int lane  = tid & 63;
    const int wave  = tid >> 6;
    const int row16 = lane & 15;
    const int grp   = lane >> 4;
    const int m0 = blockIdx.x * 128;
    const int n0 = blockIdx.y * 64;
    const int wr = (wave >> 1) * 64;
    const int wc = (wave & 1) * 32;

    f32x4 acc[4][2] = {};

    const int cA0 = wave * 64 + lane;            // 0..255
    const int cA1 = cA0 + 256;                   // 256..511
    const int rA0 = cA0 >> 2, kA0 = (cA0 & 3) * 8;
    const int rA1 = cA1 >> 2, kA1 = (cA1 & 3) * 8;
    const int rB  = cA0 >> 2, kB  = (cA0 & 3) * 8;

    for (int k0 = 0; k0 < K; k0 += 64) {
        #pragma unroll
        for (int h = 0; h < 2; ++h) {
            __builtin_amdgcn_global_load_lds(
                (const __attribute__((address_space(1))) void*)(A + (size_t)(m0 + rA0) * K + k0 + h * 32 + kA0),
                (__attribute__((address_space(3))) void*)(At + h * 4096 + wave * 512), 16, 0, 0);
            __builtin_amdgcn_global_load_lds(
                (const __attribute__((address_space(1))) void*)(A + (size_t)(m0 + rA1) * K + k0 + h * 32 + kA1),
                (__attribute__((address_space(3))) void*)(At + h * 4096 + 2048 + wave * 512), 16, 0, 0);
            __builtin_amdgcn_global_load_lds(
                (const __attribute__((address_space(1))) void*)(W + (size_t)(n0 + rB) * K + k0 + h * 32 + kB),
                (__attribute__((address_space(3))) void*)(Bt + h * 2048 + wave * 512), 16, 0, 0);
        }
        __syncthreads();

        #pragma unroll
        for (int h = 0; h < 2; ++h) {
            bf16x8 a[4], b[2];
            #pragma unroll
            for (int i = 0; i < 4; ++i)
                a[i] = *reinterpret_cast<const bf16x8*>(At + h * 4096 + (wr + i * 16 + row16) * 32 + grp * 8);
            #pragma unroll
            for (int j = 0; j < 2; ++j)
                b[j] = *reinterpret_cast<const bf16x8*>(Bt + h * 2048 + (wc + j * 16 + row16) * 32 + grp * 8);
            #pragma unroll
            for (int i = 0; i < 4; ++i)
                #pragma unroll
                for (int j = 0; j < 2; ++j)
                    acc[i][j] = mfma16(a[i], b[j], acc[i][j]);
        }
        __syncthreads();
    }

    #pragma unroll
    for (int j = 0; j < 2; ++j) {
        const int n = n0 + wc + j * 16 + row16;
        const float bv = bias[n];
        #pragma unroll
        for (int i = 0; i < 4; ++i) {
            #pragma unroll
            for (int r = 0; r < 4; ++r) {
                const int m = m0 + wr + i * 16 + grp * 4 + r;
                C[(size_t)m * N + n] = f2bf(acc[i][j][r] + bv);
            }
        }
    }
}

// Same but fp32 output (final projection).
__global__ __launch_bounds__(256) void gemm_bb_f32(
    const bf16* __restrict__ A, const bf16* __restrict__ W,
    const float* __restrict__ bias, float* __restrict__ C,
    int M, int N, int K)
{
    __shared__ bf16 At[2 * 128 * 32];
    __shared__ bf16 Bt[2 * 64 * 32];

    const int tid   = threadIdx.x;
    const int lane  = tid & 63;
    const int wave  = tid >> 6;
    const int row16 = lane & 15;
    const int grp   = lane >> 4;
    const int m0 = blockIdx.x * 128;
    const int n0 = blockIdx.y * 64;
    const int wr = (wave >> 1) * 64;
    const int wc = (wave & 1) * 32;

    f32x4 acc[4][2] = {};

    const int cA0 = wave * 64 + lane;
    const int cA1 = cA0 + 256;
    const int rA0 = cA0 >> 2, kA0 = (cA0 & 3) * 8;
    const int rA1 = cA1 >> 2, kA1 = (cA1 & 3) * 8;
    const int rB  = cA0 >> 2, kB  = (cA0 & 3) * 8;

    for (int k0 = 0; k0 < K; k0 += 64) {
        #pragma unroll
        for (int h = 0; h < 2; ++h) {
            __builtin_amdgcn_global_load_lds(
                (const __attribute__((address_space(1))) void*)(A + (size_t)(m0 + rA0) * K + k0 + h * 32 + kA0),
                (__attribute__((address_space(3))) void*)(At + h * 4096 + wave * 512), 16, 0, 0);
            __builtin_amdgcn_global_load_lds(
                (const __attribute__((address_space(1))) void*)(A + (size_t)(m0 + rA1) * K + k0 + h * 32 + kA1),
                (__attribute__((address_space(3))) void*)(At + h * 4096 + 2048 + wave * 512), 16, 0, 0);
            __builtin_amdgcn_global_load_lds(
                (const __attribute__((address_space(1))) void*)(W + (size_t)(n0 + rB) * K + k0 + h * 32 + kB),
                (__attribute__((address_space(3))) void*)(Bt + h * 2048 + wave * 512), 16, 0, 0);
        }
        __syncthreads();

        #pragma unroll
        for (int h = 0; h < 2; ++h) {
            bf16x8 a[4], b[2];
            #pragma unroll
            for (int i = 0; i < 4; ++i)
                a[i] = *reinterpret_cast<const bf16x8*>(At + h * 4096 + (wr + i * 16 + row16) * 32 + grp * 8);
            #pragma unroll
            for (int j = 0; j < 2; ++j)
                b[j] = *reinterpret_cast<const bf16x8*>(Bt + h * 2048 + (wc + j * 16 + row16) * 32 + grp * 8);
            #pragma unroll
            for (int i = 0; i < 4; ++i)
                #pragma unroll
                for (int j = 0; j < 2; ++j)
                    acc[i][j] = mfma16(a[i], b[j], acc[i][j]);
        }
        __syncthreads();
    }

    #pragma unroll
    for (int j = 0; j < 2; ++j) {
        const int n = n0 + wc + j * 16 + row16;
        const float bv = bias[n];
        #pragma unroll
        for (int i = 0; i < 4; ++i) {
            #pragma unroll
            for (int r = 0; r < 4; ++r) {
                const int m = m0 + wr + i * 16 + grp * 4 + r;
                C[(size_t)m * N + n] = acc[i][j][r] + bv;
            }
        }
    }
}

// Mixed GEMM (V-proj): A fp32 (reg-staged + native cvt), W bf16 (gload_lds).
// BK=64 two-halves.
__global__ __launch_bounds__(256) void gemm_fb(
    const float* __restrict__ A, const bf16* __restrict__ W,
    const float* __restrict__ bias, bf16* __restrict__ C,
    int M, int N, int K)
{
    __shared__ bf16 At[2 * 128 * 32];
    __shared__ bf16 Bt[2 * 64 * 32];

    const int tid   = threadIdx.x;
    const int lane  = tid & 63;
    const int wave  = tid >> 6;
    const int row16 = lane & 15;
    const int grp   = lane >> 4;
    const int m0 = blockIdx.x * 128;
    const int n0 = blockIdx.y * 64;
    const int wr = (wave >> 1) * 64;
    const int wc = (wave & 1) * 32;

    f32x4 acc[4][2] = {};

    const int cB = wave * 64 + lane;
    const int rB = cB >> 2, kB = (cB & 3) * 8;

    for (int k0 = 0; k0 < K; k0 += 64) {
        #pragma unroll
        for (int h = 0; h < 2; ++h) {
            __builtin_amdgcn_global_load_lds(
                (const __attribute__((address_space(1))) void*)(W + (size_t)(n0 + rB) * K + k0 + h * 32 + kB),
                (__attribute__((address_space(3))) void*)(Bt + h * 2048 + wave * 512), 16, 0, 0);
            #pragma unroll
            for (int i = 0; i < 4; ++i) {
                const int c   = tid + 256 * i;       // 0..1023
                const int r   = c >> 3;              // row 0..127
                const int col = (c & 7) * 4;         // 0..28
                f32x4 va = *reinterpret_cast<const f32x4*>(A + (size_t)(m0 + r) * K + k0 + h * 32 + col);
                u32x2 pa = { pack2bf(va[0], va[1]), pack2bf(va[2], va[3]) };
                *reinterpret_cast<u32x2*>(At + h * 4096 + r * 32 + col) = pa;
            }
        }
        __syncthreads();

        #pragma unroll
        for (int h = 0; h < 2; ++h) {
            bf16x8 a[4], b[2];
            #pragma unroll
            for (int i = 0; i < 4; ++i)
                a[i] = *reinterpret_cast<const bf16x8*>(At + h * 4096 + (wr + i * 16 + row16) * 32 + grp * 8);
            #pragma unroll
            for (int j = 0; j < 2; ++j)
                b[j] = *reinterpret_cast<const bf16x8*>(Bt + h * 2048 + (wc + j * 16 + row16) * 32 + grp * 8);
            #pragma unroll
            for (int i = 0; i < 4; ++i)
                #pragma unroll
                for (int j = 0; j < 2; ++j)
                    acc[i][j] = mfma16(a[i], b[j], acc[i][j]);
        }
        __syncthreads();
    }

    #pragma unroll
    for (int j = 0; j < 2; ++j) {
        const int n = n0 + wc + j * 16 + row16;
        const float bv = bias[n];
        #pragma unroll
        for (int i = 0; i < 4; ++i) {
            #pragma unroll
            for (int r = 0; r < 4; ++r) {
                const int m = m0 + wr + i * 16 + grp * 4 + r;
                C[(size_t)m * N + n] = f2bf(acc[i][j][r] + bv);
            }
        }
    }
}

// Flash attention, swapped-QK^T 32x32 + combined softmax + defer-max (r20)
// + T14 async-STAGE split: tile t+1's K/V global loads are issued into
// registers BEFORE computing tile t; after the post-compute barrier the regs
// are written to LDS (HBM latency hides under the MFMA/softmax of tile t).
__global__ __launch_bounds__(256) void attn_fwd(
    const bf16* __restrict__ Q, const bf16* __restrict__ K,
    const bf16* __restrict__ V, bf16* __restrict__ Y)
{
    constexpr int LDK = 72;
    constexpr int LDV = 72;
    constexpr int LDP = 40;
    __shared__ bf16 Kt[64 * LDK];
    __shared__ bf16 Vt[64 * LDV];
    __shared__ bf16 Pt[4 * 32 * LDP];

    const int tid  = threadIdx.x;
    const int lane = tid & 63;
    const int wave = tid >> 6;
    const int l31  = lane & 31;
    const int hi   = lane >> 5;
    const int bh = blockIdx.y;
    const size_t base = (size_t)(bh >> 4) * NS * ND + (size_t)(bh & 15) * NHD;
    const int q0 = blockIdx.x * 128 + wave * 32;

    const float qscale = 0.125f * 1.44269504f;
    bf16x8 qB[4];
    {
        const bf16* qp = Q + base + (size_t)(q0 + l31) * ND + hi * 8;
        #pragma unroll
        for (int c = 0; c < 4; ++c) {
            bf16x8 t = *reinterpret_cast<const bf16x8*>(qp + c * 16);
            #pragma unroll
            for (int j = 0; j < 8; ++j) qB[c][j] = f2bf(bf2f(t[j]) * qscale);
        }
    }

    float mrow = -INFINITY, lrow = 0.f;
    f32x16 yacc0 = {}, yacc1 = {};

    const int a8  = tid & 7;
    const int rk  = tid >> 3;            // K rows rk, rk+32
    const int e0  = a8 * 8;
    const int rp  = tid >> 3;            // V row-pair
    const int d0  = a8 * 8;

    bf16* const ptW = Pt + wave * 32 * LDP;

    // staging registers (one set: loaded for t+1, written after barrier)
    bf16x8 kr0, kr1, vr0, vr1;

    // prologue: stage tile 0
    kr0 = *reinterpret_cast<const bf16x8*>(K + base + (size_t)(rk) * ND + e0);
    kr1 = *reinterpret_cast<const bf16x8*>(K + base + (size_t)(rk + 32) * ND + e0);
    vr0 = *reinterpret_cast<const bf16x8*>(V + base + (size_t)(2 * rp) * ND + d0);
    vr1 = *reinterpret_cast<const bf16x8*>(V + base + (size_t)(2 * rp) * ND + ND + d0);
    {
        *reinterpret_cast<bf16x8*>(Kt + rk * LDK + e0) = kr0;
        *reinterpret_cast<bf16x8*>(Kt + (rk + 32) * LDK + e0) = kr1;
        #pragma unroll
        for (int j = 0; j < 8; ++j) {
            const int jj = (j + a8) & 7;
            bf16x2 pr = { vr0[jj], vr1[jj] };
            *reinterpret_cast<u32*>(Vt + (d0 + jj) * LDV + 2 * rp) =
                __builtin_bit_cast(u32, pr);
        }
    }
    __syncthreads();

    for (int k0 = 0; k0 < NS; k0 += 64) {
        const bool more = (k0 + 64 < NS);
        if (more) {   // issue next tile's loads EARLY (latency hides under compute)
            kr0 = *reinterpret_cast<const bf16x8*>(K + base + (size_t)(k0 + 64 + rk) * ND + e0);
            kr1 = *reinterpret_cast<const bf16x8*>(K + base + (size_t)(k0 + 64 + rk + 32) * ND + e0);
            vr0 = *reinterpret_cast<const bf16x8*>(V + base + (size_t)(k0 + 64 + 2 * rp) * ND + d0);
            vr1 = *reinterpret_cast<const bf16x8*>(V + base + (size_t)(k0 + 64 + 2 * rp) * ND + ND + d0);
        }

        // ---- S for BOTH subtiles ----
        f32x16 s0 = {}, s1 = {};
        #pragma unroll
        for (int c = 0; c < 4; ++c) {
            bf16x8 kf = *reinterpret_cast<const bf16x8*>(
                Kt + l31 * LDK + c * 16 + hi * 8);
            s0 = mfma32(kf, qB[c], s0);
        }
        #pragma unroll
        for (int c = 0; c < 4; ++c) {
            bf16x8 kf = *reinterpret_cast<const bf16x8*>(
                Kt + (32 + l31) * LDK + c * 16 + hi * 8);
            s1 = mfma32(kf, qB[c], s1);
        }

        // ---- combined softmax over 64 k ----
        float rmax = s0[0];
        #pragma unroll
        for (int i = 1; i < 16; ++i) rmax = fmaxf(rmax, s0[i]);
        #pragma unroll
        for (int i = 0; i < 16; ++i) rmax = fmaxf(rmax, s1[i]);
        rmax = fmaxf(rmax, __shfl_xor(rmax, 32));
        if (!__all(rmax <= mrow + 8.0f)) {       // defer-max: rare rescale
            const float mnew = fmaxf(mrow, rmax);
            const float corr = exp2f(mrow - mnew);
            lrow *= corr;
            #pragma unroll
            for (int i = 0; i < 16; ++i) { yacc0[i] *= corr; yacc1[i] *= corr; }
            mrow = mnew;
        }
        float psum = 0.f;
        #pragma unroll
        for (int i = 0; i < 16; ++i) { s0[i] = exp2f(s0[i] - mrow); psum += s0[i]; }
        #pragma unroll
        for (int i = 0; i < 16; ++i) { s1[i] = exp2f(s1[i] - mrow); psum += s1[i]; }
        lrow += psum;

        // ---- subtile 0: P -> LDS, PV ----
        #pragma unroll
        for (int cp = 0; cp < 4; ++cp) {
            u32x2 pw = { pack2bf(s0[4 * cp + 0], s0[4 * cp + 1]),
                         pack2bf(s0[4 * cp + 2], s0[4 * cp + 3]) };
            *reinterpret_cast<u32x2*>(ptW + l31 * LDP + 8 * cp + 4 * hi) = pw;
        }
        #pragma unroll
        for (int kc = 0; kc < 2; ++kc) {
            bf16x8 pf = *reinterpret_cast<const bf16x8*>(
                ptW + l31 * LDP + kc * 16 + hi * 8);
            bf16x8 vf0 = *reinterpret_cast<const bf16x8*>(
                Vt + l31 * LDV + kc * 16 + hi * 8);
            bf16x8 vf1 = *reinterpret_cast<const bf16x8*>(
                Vt + (32 + l31) * LDV + kc * 16 + hi * 8);
            yacc0 = mfma32(vf0, pf, yacc0);
            yacc1 = mfma32(vf1, pf, yacc1);
        }
        // ---- subtile 1: P -> LDS, PV ----
        #pragma unroll
        for (int cp = 0; cp < 4; ++cp) {
            u32x2 pw = { pack2bf(s1[4 * cp + 0], s1[4 * cp + 1]),
                         pack2bf(s1[4 * cp + 2], s1[4 * cp + 3]) };
            *reinterpret_cast<u32x2*>(ptW + l31 * LDP + 8 * cp + 4 * hi) = pw;
        }
        #pragma unroll
        for (int kc = 0; kc < 2; ++kc) {
            bf16x8 pf = *reinterpret_cast<const bf16x8*>(
                ptW + l31 * LDP + kc * 16 + hi * 8);
            bf16x8 vf0 = *reinterpret_cast<const bf16x8*>(
                Vt + l31 * LDV + 32 + kc * 16 + hi * 8);
            bf16x8 vf1 = *reinterpret_cast<const bf16x8*>(
                Vt + (32 + l31) * LDV + 32 + kc * 16 + hi * 8);
            yacc0 = mfma32(vf0, pf, yacc0);
            yacc1 = mfma32(vf1, pf, yacc1);
        }

        __syncthreads();                 // all waves done reading Kt/Vt
        if (more) {                      // write pre-loaded t+1 (data arrived)
            *reinterpret_cast<bf16x8*>(Kt + rk * LDK + e0) = kr0;
            *reinterpret_cast<bf16x8*>(Kt + (rk + 32) * LDK + e0) = kr1;
            #pragma unroll
            for (int j = 0; j < 8; ++j) {
                const int jj = (j + a8) & 7;
                bf16x2 pr = { vr0[jj], vr1[jj] };
                *reinterpret_cast<u32*>(Vt + (d0 + jj) * LDV + 2 * rp) =
                    __builtin_bit_cast(u32, pr);
            }
        }
        __syncthreads();                 // t+1 tile visible
    }

    lrow += __shfl_xor(lrow, 32);
    const float inv = 1.f / lrow;
    bf16* yp = Y + base + (size_t)(q0 + l31) * ND;
    #pragma unroll
    for (int cp = 0; cp < 4; ++cp) {
        bf16x4 o0 = { f2bf(yacc0[4*cp+0] * inv), f2bf(yacc0[4*cp+1] * inv),
                      f2bf(yacc0[4*cp+2] * inv), f2bf(yacc0[4*cp+3] * inv) };
        bf16x4 o1 = { f2bf(yacc1[4*cp+0] * inv), f2bf(yacc1[4*cp+1] * inv),
                      f2bf(yacc1[4*cp+2] * inv), f2bf(yacc1[4*cp+3] * inv) };
        *reinterpret_cast<bf16x4*>(yp + 8 * cp + 4 * hi)      = o0;
        *reinterpret_cast<bf16x4*>(yp + 32 + 8 * cp + 4 * hi) = o1;
    }
}

extern "C" void kernel_launch(void* const* d_in, const int* in_sizes, int n_in,
                              void* d_out, int out_size, void* d_ws, size_t ws_size,
                              hipStream_t stream) {
    float* outF = (float*)d_out;   // OUTPUT IS FLOAT32

    int c4 = 0, cW = 0, cB = 0;
    for (int i = 0; i < n_in; ++i) {
        if (in_sizes[i] == NB * NS * ND) ++c4;
        else if (in_sizes[i] == ND * ND) ++cW;
        else if (in_sizes[i] == ND) ++cB;
    }
    if (c4 != 3 || cW != 4 || cB != 4) {
        write_marker_f<<<1, 1, 0, stream>>>(outF, 2.0f);
        return;
    }
    const size_t tsz = (size_t)NB * NS * ND;       // 4194304
    if (ws_size < 2 * tsz * sizeof(bf16)) {        // 16 MiB
        write_marker_f<<<1, 1, 0, stream>>>(outF, 1.0f);
        return;
    }

    const float* q  = (const float*)d_in[0];
    const float* k  = (const float*)d_in[1];
    const float* v  = (const float*)d_in[2];
    const float* Wq = (const float*)d_in[4];
    const float* bq = (const float*)d_in[5];
    const float* Wk = (const float*)d_in[6];
    const float* bk = (const float*)d_in[7];
    const float* Wv = (const float*)d_in[8];
    const float* bv = (const float*)d_in[9];
    const float* Wo = (const float*)d_in[10];
    const float* bo = (const float*)d_in[11];

    // Scratch choreography (race-checked, r19):
    //  S0 = ws[0:8MB]   : Qb, then Y (attn in-place, disjoint slices)
    //  S1 = ws[8:16MB]  : Wq|Wk|Wv|Wo bf16 (written once, read-only after)
    //  D0 = d_out[0:8MB]: qbf -> kbf -> Vb (dead before final GEMM)
    //  D1 = d_out[8:16MB]: Kb              (dead before final GEMM)
    bf16* S0 = (bf16*)d_ws;
    bf16* S1 = S0 + tsz;
    bf16* D0 = (bf16*)d_out;
    bf16* D1 = D0 + tsz;
    const size_t wsz = (size_t)ND * ND;

    const int M = NB * NS;
    dim3 gg(M / 128, ND / 64);

    cvt4_f32_bf16<<<(int)(4 * wsz / 8 / 256), 256, 0, stream>>>(
        Wq, Wk, Wv, Wo, S1, (int)(wsz / 8));
    cvt_f32_bf16<<<(int)(tsz / 8 / 256), 256, 0, stream>>>(q, D0, (int)(tsz / 8));
    gemm_bb<<<gg, 256, 0, stream>>>(D0, S1 + 0 * wsz, bq, S0, M, ND, ND);
    cvt_f32_bf16<<<(int)(tsz / 8 / 256), 256, 0, stream>>>(k, D0, (int)(tsz / 8));
    gemm_bb<<<gg, 256, 0, stream>>>(D0, S1 + 1 * wsz, bk, D1, M, ND, ND);
    gemm_fb<<<gg, 256, 0, stream>>>(v, S1 + 2 * wsz, bv, D0, M, ND, ND);
    attn_fwd<<<dim3(NS / 128, NB * NH), 256, 0, stream>>>(S0, D1, D0, S0);
    gemm_bb_f32<<<gg, 256, 0, stream>>>(S0, S1 + 3 * wsz, bo, outF, M, ND, ND);
}

// Round 22
// 175.923 us; speedup vs baseline: 1.2614x; 1.0418x over previous
//
#include <hip/hip_runtime.h>
#include <math.h>

// Shapes (fixed by the problem)
#define NB 2
#define NS 2048
#define ND 1024
#define NH 16
#define NHD 64

typedef __bf16 bf16;
typedef __attribute__((ext_vector_type(2))) __bf16 bf16x2;
typedef __attribute__((ext_vector_type(4))) __bf16 bf16x4;
typedef __attribute__((ext_vector_type(8))) __bf16 bf16x8;
typedef __attribute__((ext_vector_type(4))) float f32x4;
typedef __attribute__((ext_vector_type(16))) float f32x16;
typedef unsigned int u32;
typedef __attribute__((ext_vector_type(2))) unsigned int u32x2;
typedef __attribute__((ext_vector_type(4))) unsigned int u32x4;

__device__ __forceinline__ float bf2f(bf16 x) {
    unsigned int w = ((unsigned int)__builtin_bit_cast(unsigned short, x)) << 16;
    return __builtin_bit_cast(float, w);
}
__device__ __forceinline__ bf16 f2bf(float f) { return (bf16)f; }
__device__ __forceinline__ u32 pack2bf(float a, float b) {
    bf16x2 t = { (bf16)a, (bf16)b };
    return __builtin_bit_cast(u32, t);
}

__device__ __forceinline__ f32x4 mfma16(bf16x8 a, bf16x8 b, f32x4 c) {
    return __builtin_amdgcn_mfma_f32_16x16x32_bf16(a, b, c, 0, 0, 0);
}
__device__ __forceinline__ f32x16 mfma32(bf16x8 a, bf16x8 b, f32x16 c) {
    return __builtin_amdgcn_mfma_f32_32x32x16_bf16(a, b, c, 0, 0, 0);
}

__global__ void write_marker_f(float* out, float v) { out[0] = v; }

// Fused fp32->bf16 conversion of q, k, and the 4 weight matrices (1 launch).
// Index space: [0,tn8) -> q, [tn8,2*tn8) -> k, then 4 x wn8 -> weights.
__global__ __launch_bounds__(256) void cvt_all(
    const float* __restrict__ q, const float* __restrict__ k,
    const float* __restrict__ w0, const float* __restrict__ w1,
    const float* __restrict__ w2, const float* __restrict__ w3,
    bf16* __restrict__ qd, bf16* __restrict__ kd, bf16* __restrict__ wd,
    int tn8, int wn8)
{
    const int i = blockIdx.x * 256 + threadIdx.x;
    const float* src; bf16* dst; int j;
    if (i < tn8)              { src = q;  dst = qd; j = i; }
    else if (i < 2 * tn8)     { src = k;  dst = kd; j = i - tn8; }
    else {
        const int r = i - 2 * tn8;
        const int t = r / wn8;                // 0..3, block-uniform (wn8 % 256 == 0)
        j = r - t * wn8;
        src = (t == 0) ? w0 : (t == 1) ? w1 : (t == 2) ? w2 : w3;
        dst = wd + (size_t)t * (size_t)wn8 * 8;
    }
    const f32x4* s4 = reinterpret_cast<const f32x4*>(src) + 2 * (size_t)j;
    f32x4 a = s4[0], b = s4[1];
    u32x4 p = { pack2bf(a[0], a[1]), pack2bf(a[2], a[3]),
                pack2bf(b[0], b[1]), pack2bf(b[2], b[3]) };
    *reinterpret_cast<u32x4*>(dst + 8 * (size_t)j) = p;
}

// Pure-bf16 GEMM: C = A @ W^T + bias, bf16 out. 128x64 tile, BK=64 staged as
// two 32-k LDS halves, global_load_lds(16B). (r21, unchanged)
__global__ __launch_bounds__(256) void gemm_bb(
    const bf16* __restrict__ A, const bf16* __restrict__ W,
    const float* __restrict__ bias, bf16* __restrict__ C,
    int M, int N, int K)
{
    __shared__ bf16 At[2 * 128 * 32];
    __shared__ bf16 Bt[2 * 64 * 32];

    const int tid   = threadIdx.x;
    const int lane  = tid & 63;
    const int wave  = tid >> 6;
    const int row16 = lane & 15;
    const int grp   = lane >> 4;
    const int m0 = blockIdx.x * 128;
    const int n0 = blockIdx.y * 64;
    const int wr = (wave >> 1) * 64;
    const int wc = (wave & 1) * 32;

    f32x4 acc[4][2] = {};

    const int cA0 = wave * 64 + lane;
    const int cA1 = cA0 + 256;
    const int rA0 = cA0 >> 2, kA0 = (cA0 & 3) * 8;
    const int rA1 = cA1 >> 2, kA1 = (cA1 & 3) * 8;
    const int rB  = cA0 >> 2, kB  = (cA0 & 3) * 8;

    for (int k0 = 0; k0 < K; k0 += 64) {
        #pragma unroll
        for (int h = 0; h < 2; ++h) {
            __builtin_amdgcn_global_load_lds(
                (const __attribute__((address_space(1))) void*)(A + (size_t)(m0 + rA0) * K + k0 + h * 32 + kA0),
                (__attribute__((address_space(3))) void*)(At + h * 4096 + wave * 512), 16, 0, 0);
            __builtin_amdgcn_global_load_lds(
                (const __attribute__((address_space(1))) void*)(A + (size_t)(m0 + rA1) * K + k0 + h * 32 + kA1),
                (__attribute__((address_space(3))) void*)(At + h * 4096 + 2048 + wave * 512), 16, 0, 0);
            __builtin_amdgcn_global_load_lds(
                (const __attribute__((address_space(1))) void*)(W + (size_t)(n0 + rB) * K + k0 + h * 32 + kB),
                (__attribute__((address_space(3))) void*)(Bt + h * 2048 + wave * 512), 16, 0, 0);
        }
        __syncthreads();

        #pragma unroll
        for (int h = 0; h < 2; ++h) {
            bf16x8 a[4], b[2];
            #pragma unroll
            for (int i = 0; i < 4; ++i)
                a[i] = *reinterpret_cast<const bf16x8*>(At + h * 4096 + (wr + i * 16 + row16) * 32 + grp * 8);
            #pragma unroll
            for (int j = 0; j < 2; ++j)
                b[j] = *reinterpret_cast<const bf16x8*>(Bt + h * 2048 + (wc + j * 16 + row16) * 32 + grp * 8);
            #pragma unroll
            for (int i = 0; i < 4; ++i)
                #pragma unroll
                for (int j = 0; j < 2; ++j)
                    acc[i][j] = mfma16(a[i], b[j], acc[i][j]);
        }
        __syncthreads();
    }

    #pragma unroll
    for (int j = 0; j < 2; ++j) {
        const int n = n0 + wc + j * 16 + row16;
        const float bv = bias[n];
        #pragma unroll
        for (int i = 0; i < 4; ++i) {
            #pragma unroll
            for (int r = 0; r < 4; ++r) {
                const int m = m0 + wr + i * 16 + grp * 4 + r;
                C[(size_t)m * N + n] = f2bf(acc[i][j][r] + bv);
            }
        }
    }
}

// Same but fp32 output (final projection).
__global__ __launch_bounds__(256) void gemm_bb_f32(
    const bf16* __restrict__ A, const bf16* __restrict__ W,
    const float* __restrict__ bias, float* __restrict__ C,
    int M, int N, int K)
{
    __shared__ bf16 At[2 * 128 * 32];
    __shared__ bf16 Bt[2 * 64 * 32];

    const int tid   = threadIdx.x;
    const int lane  = tid & 63;
    const int wave  = tid >> 6;
    const int row16 = lane & 15;
    const int grp   = lane >> 4;
    const int m0 = blockIdx.x * 128;
    const int n0 = blockIdx.y * 64;
    const int wr = (wave >> 1) * 64;
    const int wc = (wave & 1) * 32;

    f32x4 acc[4][2] = {};

    const int cA0 = wave * 64 + lane;
    const int cA1 = cA0 + 256;
    const int rA0 = cA0 >> 2, kA0 = (cA0 & 3) * 8;
    const int rA1 = cA1 >> 2, kA1 = (cA1 & 3) * 8;
    const int rB  = cA0 >> 2, kB  = (cA0 & 3) * 8;

    for (int k0 = 0; k0 < K; k0 += 64) {
        #pragma unroll
        for (int h = 0; h < 2; ++h) {
            __builtin_amdgcn_global_load_lds(
                (const __attribute__((address_space(1))) void*)(A + (size_t)(m0 + rA0) * K + k0 + h * 32 + kA0),
                (__attribute__((address_space(3))) void*)(At + h * 4096 + wave * 512), 16, 0, 0);
            __builtin_amdgcn_global_load_lds(
                (const __attribute__((address_space(1))) void*)(A + (size_t)(m0 + rA1) * K + k0 + h * 32 + kA1),
                (__attribute__((address_space(3))) void*)(At + h * 4096 + 2048 + wave * 512), 16, 0, 0);
            __builtin_amdgcn_global_load_lds(
                (const __attribute__((address_space(1))) void*)(W + (size_t)(n0 + rB) * K + k0 + h * 32 + kB),
                (__attribute__((address_space(3))) void*)(Bt + h * 2048 + wave * 512), 16, 0, 0);
        }
        __syncthreads();

        #pragma unroll
        for (int h = 0; h < 2; ++h) {
            bf16x8 a[4], b[2];
            #pragma unroll
            for (int i = 0; i < 4; ++i)
                a[i] = *reinterpret_cast<const bf16x8*>(At + h * 4096 + (wr + i * 16 + row16) * 32 + grp * 8);
            #pragma unroll
            for (int j = 0; j < 2; ++j)
                b[j] = *reinterpret_cast<const bf16x8*>(Bt + h * 2048 + (wc + j * 16 + row16) * 32 + grp * 8);
            #pragma unroll
            for (int i = 0; i < 4; ++i)
                #pragma unroll
                for (int j = 0; j < 2; ++j)
                    acc[i][j] = mfma16(a[i], b[j], acc[i][j]);
        }
        __syncthreads();
    }

    #pragma unroll
    for (int j = 0; j < 2; ++j) {
        const int n = n0 + wc + j * 16 + row16;
        const float bv = bias[n];
        #pragma unroll
        for (int i = 0; i < 4; ++i) {
            #pragma unroll
            for (int r = 0; r < 4; ++r) {
                const int m = m0 + wr + i * 16 + grp * 4 + r;
                C[(size_t)m * N + n] = acc[i][j][r] + bv;
            }
        }
    }
}

// Mixed GEMM (V-proj): A fp32 (reg-staged + native cvt), W bf16 (gload_lds).
__global__ __launch_bounds__(256) void gemm_fb(
    const float* __restrict__ A, const bf16* __restrict__ W,
    const float* __restrict__ bias, bf16* __restrict__ C,
    int M, int N, int K)
{
    __shared__ bf16 At[2 * 128 * 32];
    __shared__ bf16 Bt[2 * 64 * 32];

    const int tid   = threadIdx.x;
    const int lane  = tid & 63;
    const int wave  = tid >> 6;
    const int row16 = lane & 15;
    const int grp   = lane >> 4;
    const int m0 = blockIdx.x * 128;
    const int n0 = blockIdx.y * 64;
    const int wr = (wave >> 1) * 64;
    const int wc = (wave & 1) * 32;

    f32x4 acc[4][2] = {};

    const int cB = wave * 64 + lane;
    const int rB = cB >> 2, kB = (cB & 3) * 8;

    for (int k0 = 0; k0 < K; k0 += 64) {
        #pragma unroll
        for (int h = 0; h < 2; ++h) {
            __builtin_amdgcn_global_load_lds(
                (const __attribute__((address_space(1))) void*)(W + (size_t)(n0 + rB) * K + k0 + h * 32 + kB),
                (__attribute__((address_space(3))) void*)(Bt + h * 2048 + wave * 512), 16, 0, 0);
            #pragma unroll
            for (int i = 0; i < 4; ++i) {
                const int c   = tid + 256 * i;
                const int r   = c >> 3;
                const int col = (c & 7) * 4;
                f32x4 va = *reinterpret_cast<const f32x4*>(A + (size_t)(m0 + r) * K + k0 + h * 32 + col);
                u32x2 pa = { pack2bf(va[0], va[1]), pack2bf(va[2], va[3]) };
                *reinterpret_cast<u32x2*>(At + h * 4096 + r * 32 + col) = pa;
            }
        }
        __syncthreads();

        #pragma unroll
        for (int h = 0; h < 2; ++h) {
            bf16x8 a[4], b[2];
            #pragma unroll
            for (int i = 0; i < 4; ++i)
                a[i] = *reinterpret_cast<const bf16x8*>(At + h * 4096 + (wr + i * 16 + row16) * 32 + grp * 8);
            #pragma unroll
            for (int j = 0; j < 2; ++j)
                b[j] = *reinterpret_cast<const bf16x8*>(Bt + h * 2048 + (wc + j * 16 + row16) * 32 + grp * 8);
            #pragma unroll
            for (int i = 0; i < 4; ++i)
                #pragma unroll
                for (int j = 0; j < 2; ++j)
                    acc[i][j] = mfma16(a[i], b[j], acc[i][j]);
        }
        __syncthreads();
    }

    #pragma unroll
    for (int j = 0; j < 2; ++j) {
        const int n = n0 + wc + j * 16 + row16;
        const float bv = bias[n];
        #pragma unroll
        for (int i = 0; i < 4; ++i) {
            #pragma unroll
            for (int r = 0; r < 4; ++r) {
                const int m = m0 + wr + i * 16 + grp * 4 + r;
                C[(size_t)m * N + n] = f2bf(acc[i][j][r] + bv);
            }
        }
    }
}

// Flash attention, swapped-QK^T 32x32 + combined softmax + defer-max +
// async-STAGE (r21) + NEW: double-buffered K/V LDS -> ONE barrier per tile,
// and tree-reduced max/psum chains (depth 5, max3-fusable).
__global__ __launch_bounds__(256) void attn_fwd(
    const bf16* __restrict__ Q, const bf16* __restrict__ K,
    const bf16* __restrict__ V, bf16* __restrict__ Y)
{
    constexpr int LDK = 72;
    constexpr int LDV = 72;
    constexpr int LDP = 40;
    __shared__ bf16 Kt[2 * 64 * LDK];      // double-buffered
    __shared__ bf16 Vt[2 * 64 * LDV];
    __shared__ bf16 Pt[4 * 32 * LDP];

    const int tid  = threadIdx.x;
    const int lane = tid & 63;
    const int wave = tid >> 6;
    const int l31  = lane & 31;
    const int hi   = lane >> 5;
    const int bh = blockIdx.y;
    const size_t base = (size_t)(bh >> 4) * NS * ND + (size_t)(bh & 15) * NHD;
    const int q0 = blockIdx.x * 128 + wave * 32;

    const float qscale = 0.125f * 1.44269504f;
    bf16x8 qB[4];
    {
        const bf16* qp = Q + base + (size_t)(q0 + l31) * ND + hi * 8;
        #pragma unroll
        for (int c = 0; c < 4; ++c) {
            bf16x8 t = *reinterpret_cast<const bf16x8*>(qp + c * 16);
            #pragma unroll
            for (int j = 0; j < 8; ++j) qB[c][j] = f2bf(bf2f(t[j]) * qscale);
        }
    }

    float mrow = -INFINITY, lrow = 0.f;
    f32x16 yacc0 = {}, yacc1 = {};

    const int a8  = tid & 7;
    const int rk  = tid >> 3;            // K rows rk, rk+32
    const int e0  = a8 * 8;
    const int rp  = tid >> 3;            // V row-pair
    const int d0  = a8 * 8;

    bf16* const ptW = Pt + wave * 32 * LDP;

    bf16x8 kr0, kr1, vr0, vr1;

    // prologue: stage tile 0 into buffer 0
    kr0 = *reinterpret_cast<const bf16x8*>(K + base + (size_t)(rk) * ND + e0);
    kr1 = *reinterpret_cast<const bf16x8*>(K + base + (size_t)(rk + 32) * ND + e0);
    vr0 = *reinterpret_cast<const bf16x8*>(V + base + (size_t)(2 * rp) * ND + d0);
    vr1 = *reinterpret_cast<const bf16x8*>(V + base + (size_t)(2 * rp) * ND + ND + d0);
    {
        *reinterpret_cast<bf16x8*>(Kt + rk * LDK + e0) = kr0;
        *reinterpret_cast<bf16x8*>(Kt + (rk + 32) * LDK + e0) = kr1;
        #pragma unroll
        for (int j = 0; j < 8; ++j) {
            const int jj = (j + a8) & 7;
            bf16x2 pr = { vr0[jj], vr1[jj] };
            *reinterpret_cast<u32*>(Vt + (d0 + jj) * LDV + 2 * rp) =
                __builtin_bit_cast(u32, pr);
        }
    }
    __syncthreads();

    for (int t = 0; t < NS / 64; ++t) {
        const int k0 = t * 64;
        const int B = t & 1;
        const bool more = (k0 + 64 < NS);
        const bf16* const KtB = Kt + B * 64 * LDK;
        const bf16* const VtB = Vt + B * 64 * LDV;

        if (more) {   // issue next tile's loads early
            kr0 = *reinterpret_cast<const bf16x8*>(K + base + (size_t)(k0 + 64 + rk) * ND + e0);
            kr1 = *reinterpret_cast<const bf16x8*>(K + base + (size_t)(k0 + 64 + rk + 32) * ND + e0);
            vr0 = *reinterpret_cast<const bf16x8*>(V + base + (size_t)(k0 + 64 + 2 * rp) * ND + d0);
            vr1 = *reinterpret_cast<const bf16x8*>(V + base + (size_t)(k0 + 64 + 2 * rp) * ND + ND + d0);
        }

        // ---- S for both subtiles ----
        f32x16 s0 = {}, s1 = {};
        #pragma unroll
        for (int c = 0; c < 4; ++c) {
            bf16x8 kf = *reinterpret_cast<const bf16x8*>(
                KtB + l31 * LDK + c * 16 + hi * 8);
            s0 = mfma32(kf, qB[c], s0);
        }
        #pragma unroll
        for (int c = 0; c < 4; ++c) {
            bf16x8 kf = *reinterpret_cast<const bf16x8*>(
                KtB + (32 + l31) * LDK + c * 16 + hi * 8);
            s1 = mfma32(kf, qB[c], s1);
        }

        // ---- combined softmax (tree reductions) ----
        float mx[16];
        #pragma unroll
        for (int i = 0; i < 16; ++i) mx[i] = fmaxf(s0[i], s1[i]);
        #pragma unroll
        for (int off = 8; off >= 1; off >>= 1)
            #pragma unroll
            for (int i = 0; i < 8; ++i)
                if (i < off) mx[i] = fmaxf(mx[i], mx[i + off]);
        float rmax = fmaxf(mx[0], __shfl_xor(mx[0], 32));
        if (!__all(rmax <= mrow + 8.0f)) {       // defer-max: rare rescale
            const float mnew = fmaxf(mrow, rmax);
            const float corr = exp2f(mrow - mnew);
            lrow *= corr;
            #pragma unroll
            for (int i = 0; i < 16; ++i) { yacc0[i] *= corr; yacc1[i] *= corr; }
            mrow = mnew;
        }
        #pragma unroll
        for (int i = 0; i < 16; ++i) s0[i] = exp2f(s0[i] - mrow);
        #pragma unroll
        for (int i = 0; i < 16; ++i) s1[i] = exp2f(s1[i] - mrow);
        float ps[16];
        #pragma unroll
        for (int i = 0; i < 16; ++i) ps[i] = s0[i] + s1[i];
        #pragma unroll
        for (int off = 8; off >= 1; off >>= 1)
            #pragma unroll
            for (int i = 0; i < 8; ++i)
                if (i < off) ps[i] += ps[i + off];
        lrow += ps[0];

        // ---- subtile 0: P -> LDS, PV ----
        #pragma unroll
        for (int cp = 0; cp < 4; ++cp) {
            u32x2 pw = { pack2bf(s0[4 * cp + 0], s0[4 * cp + 1]),
                         pack2bf(s0[4 * cp + 2], s0[4 * cp + 3]) };
            *reinterpret_cast<u32x2*>(ptW + l31 * LDP + 8 * cp + 4 * hi) = pw;
        }
        #pragma unroll
        for (int kc = 0; kc < 2; ++kc) {
            bf16x8 pf = *reinterpret_cast<const bf16x8*>(
                ptW + l31 * LDP + kc * 16 + hi * 8);
            bf16x8 vf0 = *reinterpret_cast<const bf16x8*>(
                VtB + l31 * LDV + kc * 16 + hi * 8);
            bf16x8 vf1 = *reinterpret_cast<const bf16x8*>(
                VtB + (32 + l31) * LDV + kc * 16 + hi * 8);
            yacc0 = mfma32(vf0, pf, yacc0);
            yacc1 = mfma32(vf1, pf, yacc1);
        }
        // ---- subtile 1 ----
        #pragma unroll
        for (int cp = 0; cp < 4; ++cp) {
            u32x2 pw = { pack2bf(s1[4 * cp + 0], s1[4 * cp + 1]),
                         pack2bf(s1[4 * cp + 2], s1[4 * cp + 3]) };
            *reinterpret_cast<u32x2*>(ptW + l31 * LDP + 8 * cp + 4 * hi) = pw;
        }
        #pragma unroll
        for (int kc = 0; kc < 2; ++kc) {
            bf16x8 pf = *reinterpret_cast<const bf16x8*>(
                ptW + l31 * LDP + kc * 16 + hi * 8);
            bf16x8 vf0 = *reinterpret_cast<const bf16x8*>(
                VtB + l31 * LDV + 32 + kc * 16 + hi * 8);
            bf16x8 vf1 = *reinterpret_cast<const bf16x8*>(
                VtB + (32 + l31) * LDV + 32 + kc * 16 + hi * 8);
            yacc0 = mfma32(vf0, pf, yacc0);
            yacc1 = mfma32(vf1, pf, yacc1);
        }

        // write pre-loaded t+1 into the OTHER buffer (safe: all waves passed
        // the end-of-(t-1) barrier, so nobody still reads buffer B^1)
        if (more) {
            bf16* const KtN = Kt + (B ^ 1) * 64 * LDK;
            bf16* const VtN = Vt + (B ^ 1) * 64 * LDV;
            *reinterpret_cast<bf16x8*>(KtN + rk * LDK + e0) = kr0;
            *reinterpret_cast<bf16x8*>(KtN + (rk + 32) * LDK + e0) = kr1;
            #pragma unroll
            for (int j = 0; j < 8; ++j) {
                const int jj = (j + a8) & 7;
                bf16x2 pr = { vr0[jj], vr1[jj] };
                *reinterpret_cast<u32*>(VtN + (d0 + jj) * LDV + 2 * rp) =
                    __builtin_bit_cast(u32, pr);
            }
        }
        __syncthreads();     // ONE barrier per tile
    }

    lrow += __shfl_xor(lrow, 32);
    const float inv = 1.f / lrow;
    bf16* yp = Y + base + (size_t)(q0 + l31) * ND;
    #pragma unroll
    for (int cp = 0; cp < 4; ++cp) {
        bf16x4 o0 = { f2bf(yacc0[4*cp+0] * inv), f2bf(yacc0[4*cp+1] * inv),
                      f2bf(yacc0[4*cp+2] * inv), f2bf(yacc0[4*cp+3] * inv) };
        bf16x4 o1 = { f2bf(yacc1[4*cp+0] * inv), f2bf(yacc1[4*cp+1] * inv),
                      f2bf(yacc1[4*cp+2] * inv), f2bf(yacc1[4*cp+3] * inv) };
        *reinterpret_cast<bf16x4*>(yp + 8 * cp + 4 * hi)      = o0;
        *reinterpret_cast<bf16x4*>(yp + 32 + 8 * cp + 4 * hi) = o1;
    }
}

extern "C" void kernel_launch(void* const* d_in, const int* in_sizes, int n_in,
                              void* d_out, int out_size, void* d_ws, size_t ws_size,
                              hipStream_t stream) {
    float* outF = (float*)d_out;   // OUTPUT IS FLOAT32

    int c4 = 0, cW = 0, cB = 0;
    for (int i = 0; i < n_in; ++i) {
        if (in_sizes[i] == NB * NS * ND) ++c4;
        else if (in_sizes[i] == ND * ND) ++cW;
        else if (in_sizes[i] == ND) ++cB;
    }
    if (c4 != 3 || cW != 4 || cB != 4) {
        write_marker_f<<<1, 1, 0, stream>>>(outF, 2.0f);
        return;
    }
    const size_t tsz = (size_t)NB * NS * ND;       // 4194304
    if (ws_size < 2 * tsz * sizeof(bf16)) {        // 16 MiB
        write_marker_f<<<1, 1, 0, stream>>>(outF, 1.0f);
        return;
    }

    const float* q  = (const float*)d_in[0];
    const float* k  = (const float*)d_in[1];
    const float* v  = (const float*)d_in[2];
    const float* Wq = (const float*)d_in[4];
    const float* bq = (const float*)d_in[5];
    const float* Wk = (const float*)d_in[6];
    const float* bk = (const float*)d_in[7];
    const float* Wv = (const float*)d_in[8];
    const float* bv = (const float*)d_in[9];
    const float* Wo = (const float*)d_in[10];
    const float* bo = (const float*)d_in[11];

    // Buffer choreography (race-checked):
    //  cvt_all: qbf->D0, kbf->D1, weights->S1        (one launch)
    //  Qgemm:  A=D0, W=S1+0 -> Qb=S0                 (D0 dead after)
    //  Kgemm:  A=D1, W=S1+1 -> Kb=D0                 (D1 dead after)
    //  Vgemm:  A=v fp32, W=S1+2 -> Vb=D1
    //  attn:   Q=S0, K=D0, V=D1 -> Y=S0 (in-place, disjoint slices)
    //  final:  A=S0, W=S1+3 -> outF (overwrites D0|D1; Kb/Vb dead)
    bf16* S0 = (bf16*)d_ws;
    bf16* S1 = S0 + tsz;
    bf16* D0 = (bf16*)d_out;
    bf16* D1 = D0 + tsz;
    const size_t wsz = (size_t)ND * ND;

    const int M = NB * NS;
    dim3 gg(M / 128, ND / 64);

    const int tn8 = (int)(tsz / 8);                // 524288
    const int wn8 = (int)(wsz / 8);                // 131072
    cvt_all<<<(2 * tn8 + 4 * wn8) / 256, 256, 0, stream>>>(
        q, k, Wq, Wk, Wv, Wo, D0, D1, S1, tn8, wn8);
    gemm_bb<<<gg, 256, 0, stream>>>(D0, S1 + 0 * wsz, bq, S0, M, ND, ND);
    gemm_bb<<<gg, 256, 0, stream>>>(D1, S1 + 1 * wsz, bk, D0, M, ND, ND);
    gemm_fb<<<gg, 256, 0, stream>>>(v, S1 + 2 * wsz, bv, D1, M, ND, ND);
    attn_fwd<<<dim3(NS / 128, NB * NH), 256, 0, stream>>>(S0, D0, D1, S0);
    gemm_bb_f32<<<gg, 256, 0, stream>>>(S0, S1 + 3 * wsz, bo, outF, M, ND, ND);
}

// Round 23
// 154.130 us; speedup vs baseline: 1.4397x; 1.1414x over previous
//
#include <hip/hip_runtime.h>
#include <math.h>

// Shapes (fixed by the problem)
#define NB 2
#define NS 2048
#define ND 1024
#define NH 16
#define NHD 64

typedef __bf16 bf16;
typedef __attribute__((ext_vector_type(2))) __bf16 bf16x2;
typedef __attribute__((ext_vector_type(4))) __bf16 bf16x4;
typedef __attribute__((ext_vector_type(8))) __bf16 bf16x8;
typedef __attribute__((ext_vector_type(4))) float f32x4;
typedef __attribute__((ext_vector_type(16))) float f32x16;
typedef unsigned int u32;
typedef __attribute__((ext_vector_type(2))) unsigned int u32x2;
typedef __attribute__((ext_vector_type(4))) unsigned int u32x4;

__device__ __forceinline__ float bf2f(bf16 x) {
    unsigned int w = ((unsigned int)__builtin_bit_cast(unsigned short, x)) << 16;
    return __builtin_bit_cast(float, w);
}
__device__ __forceinline__ bf16 f2bf(float f) { return (bf16)f; }
__device__ __forceinline__ u32 pack2bf(float a, float b) {
    bf16x2 t = { (bf16)a, (bf16)b };
    return __builtin_bit_cast(u32, t);
}
__device__ __forceinline__ float fexp2(float x) { return __builtin_amdgcn_exp2f(x); }

__device__ __forceinline__ f32x4 mfma16(bf16x8 a, bf16x8 b, f32x4 c) {
    return __builtin_amdgcn_mfma_f32_16x16x32_bf16(a, b, c, 0, 0, 0);
}
__device__ __forceinline__ f32x16 mfma32(bf16x8 a, bf16x8 b, f32x16 c) {
    return __builtin_amdgcn_mfma_f32_32x32x16_bf16(a, b, c, 0, 0, 0);
}

__global__ void write_marker_f(float* out, float v) { out[0] = v; }

// Fused fp32->bf16 conversion of q, k, and the 4 weight matrices (1 launch).
__global__ __launch_bounds__(256) void cvt_all(
    const float* __restrict__ q, const float* __restrict__ k,
    const float* __restrict__ w0, const float* __restrict__ w1,
    const float* __restrict__ w2, const float* __restrict__ w3,
    bf16* __restrict__ qd, bf16* __restrict__ kd, bf16* __restrict__ wd,
    int tn8, int wn8)
{
    const int i = blockIdx.x * 256 + threadIdx.x;
    const float* src; bf16* dst; int j;
    if (i < tn8)              { src = q;  dst = qd; j = i; }
    else if (i < 2 * tn8)     { src = k;  dst = kd; j = i - tn8; }
    else {
        const int r = i - 2 * tn8;
        const int t = r / wn8;                // block-uniform (wn8 % 256 == 0)
        j = r - t * wn8;
        src = (t == 0) ? w0 : (t == 1) ? w1 : (t == 2) ? w2 : w3;
        dst = wd + (size_t)t * (size_t)wn8 * 8;
    }
    const f32x4* s4 = reinterpret_cast<const f32x4*>(src) + 2 * (size_t)j;
    f32x4 a = s4[0], b = s4[1];
    u32x4 p = { pack2bf(a[0], a[1]), pack2bf(a[2], a[3]),
                pack2bf(b[0], b[1]), pack2bf(b[2], b[3]) };
    *reinterpret_cast<u32x4*>(dst + 8 * (size_t)j) = p;
}

// Pure-bf16 GEMM: C = (A @ W^T + bias) * oscale, bf16 out. 128x64 tile,
// BK=64 as two 32-k LDS halves, global_load_lds(16B). oscale lets the
// Q-projection pre-scale Q for attention (K passes 1.0).
__global__ __launch_bounds__(256) void gemm_bb(
    const bf16* __restrict__ A, const bf16* __restrict__ W,
    const float* __restrict__ bias, bf16* __restrict__ C,
    int M, int N, int K, float oscale)
{
    __shared__ bf16 At[2 * 128 * 32];
    __shared__ bf16 Bt[2 * 64 * 32];

    const int tid   = threadIdx.x;
    const int lane  = tid & 63;
    const int wave  = tid >> 6;
    const int row16 = lane & 15;
    const int grp   = lane >> 4;
    const int m0 = blockIdx.x * 128;
    const int n0 = blockIdx.y * 64;
    const int wr = (wave >> 1) * 64;
    const int wc = (wave & 1) * 32;

    f32x4 acc[4][2] = {};

    const int cA0 = wave * 64 + lane;
    const int cA1 = cA0 + 256;
    const int rA0 = cA0 >> 2, kA0 = (cA0 & 3) * 8;
    const int rA1 = cA1 >> 2, kA1 = (cA1 & 3) * 8;
    const int rB  = cA0 >> 2, kB  = (cA0 & 3) * 8;

    for (int k0 = 0; k0 < K; k0 += 64) {
        #pragma unroll
        for (int h = 0; h < 2; ++h) {
            __builtin_amdgcn_global_load_lds(
                (const __attribute__((address_space(1))) void*)(A + (size_t)(m0 + rA0) * K + k0 + h * 32 + kA0),
                (__attribute__((address_space(3))) void*)(At + h * 4096 + wave * 512), 16, 0, 0);
            __builtin_amdgcn_global_load_lds(
                (const __attribute__((address_space(1))) void*)(A + (size_t)(m0 + rA1) * K + k0 + h * 32 + kA1),
                (__attribute__((address_space(3))) void*)(At + h * 4096 + 2048 + wave * 512), 16, 0, 0);
            __builtin_amdgcn_global_load_lds(
                (const __attribute__((address_space(1))) void*)(W + (size_t)(n0 + rB) * K + k0 + h * 32 + kB),
                (__attribute__((address_space(3))) void*)(Bt + h * 2048 + wave * 512), 16, 0, 0);
        }
        __syncthreads();

        #pragma unroll
        for (int h = 0; h < 2; ++h) {
            bf16x8 a[4], b[2];
            #pragma unroll
            for (int i = 0; i < 4; ++i)
                a[i] = *reinterpret_cast<const bf16x8*>(At + h * 4096 + (wr + i * 16 + row16) * 32 + grp * 8);
            #pragma unroll
            for (int j = 0; j < 2; ++j)
                b[j] = *reinterpret_cast<const bf16x8*>(Bt + h * 2048 + (wc + j * 16 + row16) * 32 + grp * 8);
            #pragma unroll
            for (int i = 0; i < 4; ++i)
                #pragma unroll
                for (int j = 0; j < 2; ++j)
                    acc[i][j] = mfma16(a[i], b[j], acc[i][j]);
        }
        __syncthreads();
    }

    #pragma unroll
    for (int j = 0; j < 2; ++j) {
        const int n = n0 + wc + j * 16 + row16;
        const float bv = bias[n];
        #pragma unroll
        for (int i = 0; i < 4; ++i) {
            #pragma unroll
            for (int r = 0; r < 4; ++r) {
                const int m = m0 + wr + i * 16 + grp * 4 + r;
                C[(size_t)m * N + n] = f2bf((acc[i][j][r] + bv) * oscale);
            }
        }
    }
}

// Same but fp32 output (final projection).
__global__ __launch_bounds__(256) void gemm_bb_f32(
    const bf16* __restrict__ A, const bf16* __restrict__ W,
    const float* __restrict__ bias, float* __restrict__ C,
    int M, int N, int K)
{
    __shared__ bf16 At[2 * 128 * 32];
    __shared__ bf16 Bt[2 * 64 * 32];

    const int tid   = threadIdx.x;
    const int lane  = tid & 63;
    const int wave  = tid >> 6;
    const int row16 = lane & 15;
    const int grp   = lane >> 4;
    const int m0 = blockIdx.x * 128;
    const int n0 = blockIdx.y * 64;
    const int wr = (wave >> 1) * 64;
    const int wc = (wave & 1) * 32;

    f32x4 acc[4][2] = {};

    const int cA0 = wave * 64 + lane;
    const int cA1 = cA0 + 256;
    const int rA0 = cA0 >> 2, kA0 = (cA0 & 3) * 8;
    const int rA1 = cA1 >> 2, kA1 = (cA1 & 3) * 8;
    const int rB  = cA0 >> 2, kB  = (cA0 & 3) * 8;

    for (int k0 = 0; k0 < K; k0 += 64) {
        #pragma unroll
        for (int h = 0; h < 2; ++h) {
            __builtin_amdgcn_global_load_lds(
                (const __attribute__((address_space(1))) void*)(A + (size_t)(m0 + rA0) * K + k0 + h * 32 + kA0),
                (__attribute__((address_space(3))) void*)(At + h * 4096 + wave * 512), 16, 0, 0);
            __builtin_amdgcn_global_load_lds(
                (const __attribute__((address_space(1))) void*)(A + (size_t)(m0 + rA1) * K + k0 + h * 32 + kA1),
                (__attribute__((address_space(3))) void*)(At + h * 4096 + 2048 + wave * 512), 16, 0, 0);
            __builtin_amdgcn_global_load_lds(
                (const __attribute__((address_space(1))) void*)(W + (size_t)(n0 + rB) * K + k0 + h * 32 + kB),
                (__attribute__((address_space(3))) void*)(Bt + h * 2048 + wave * 512), 16, 0, 0);
        }
        __syncthreads();

        #pragma unroll
        for (int h = 0; h < 2; ++h) {
            bf16x8 a[4], b[2];
            #pragma unroll
            for (int i = 0; i < 4; ++i)
                a[i] = *reinterpret_cast<const bf16x8*>(At + h * 4096 + (wr + i * 16 + row16) * 32 + grp * 8);
            #pragma unroll
            for (int j = 0; j < 2; ++j)
                b[j] = *reinterpret_cast<const bf16x8*>(Bt + h * 2048 + (wc + j * 16 + row16) * 32 + grp * 8);
            #pragma unroll
            for (int i = 0; i < 4; ++i)
                #pragma unroll
                for (int j = 0; j < 2; ++j)
                    acc[i][j] = mfma16(a[i], b[j], acc[i][j]);
        }
        __syncthreads();
    }

    #pragma unroll
    for (int j = 0; j < 2; ++j) {
        const int n = n0 + wc + j * 16 + row16;
        const float bv = bias[n];
        #pragma unroll
        for (int i = 0; i < 4; ++i) {
            #pragma unroll
            for (int r = 0; r < 4; ++r) {
                const int m = m0 + wr + i * 16 + grp * 4 + r;
                C[(size_t)m * N + n] = acc[i][j][r] + bv;
            }
        }
    }
}

// Mixed GEMM (V-proj): A fp32 (reg-staged + native cvt), W bf16 (gload_lds).
__global__ __launch_bounds__(256) void gemm_fb(
    const float* __restrict__ A, const bf16* __restrict__ W,
    const float* __restrict__ bias, bf16* __restrict__ C,
    int M, int N, int K)
{
    __shared__ bf16 At[2 * 128 * 32];
    __shared__ bf16 Bt[2 * 64 * 32];

    const int tid   = threadIdx.x;
    const int lane  = tid & 63;
    const int wave  = tid >> 6;
    const int row16 = lane & 15;
    const int grp   = lane >> 4;
    const int m0 = blockIdx.x * 128;
    const int n0 = blockIdx.y * 64;
    const int wr = (wave >> 1) * 64;
    const int wc = (wave & 1) * 32;

    f32x4 acc[4][2] = {};

    const int cB = wave * 64 + lane;
    const int rB = cB >> 2, kB = (cB & 3) * 8;

    for (int k0 = 0; k0 < K; k0 += 64) {
        #pragma unroll
        for (int h = 0; h < 2; ++h) {
            __builtin_amdgcn_global_load_lds(
                (const __attribute__((address_space(1))) void*)(W + (size_t)(n0 + rB) * K + k0 + h * 32 + kB),
                (__attribute__((address_space(3))) void*)(Bt + h * 2048 + wave * 512), 16, 0, 0);
            #pragma unroll
            for (int i = 0; i < 4; ++i) {
                const int c   = tid + 256 * i;
                const int r   = c >> 3;
                const int col = (c & 7) * 4;
                f32x4 va = *reinterpret_cast<const f32x4*>(A + (size_t)(m0 + r) * K + k0 + h * 32 + col);
                u32x2 pa = { pack2bf(va[0], va[1]), pack2bf(va[2], va[3]) };
                *reinterpret_cast<u32x2*>(At + h * 4096 + r * 32 + col) = pa;
            }
        }
        __syncthreads();

        #pragma unroll
        for (int h = 0; h < 2; ++h) {
            bf16x8 a[4], b[2];
            #pragma unroll
            for (int i = 0; i < 4; ++i)
                a[i] = *reinterpret_cast<const bf16x8*>(At + h * 4096 + (wr + i * 16 + row16) * 32 + grp * 8);
            #pragma unroll
            for (int j = 0; j < 2; ++j)
                b[j] = *reinterpret_cast<const bf16x8*>(Bt + h * 2048 + (wc + j * 16 + row16) * 32 + grp * 8);
            #pragma unroll
            for (int i = 0; i < 4; ++i)
                #pragma unroll
                for (int j = 0; j < 2; ++j)
                    acc[i][j] = mfma16(a[i], b[j], acc[i][j]);
        }
        __syncthreads();
    }

    #pragma unroll
    for (int j = 0; j < 2; ++j) {
        const int n = n0 + wc + j * 16 + row16;
        const float bv = bias[n];
        #pragma unroll
        for (int i = 0; i < 4; ++i) {
            #pragma unroll
            for (int r = 0; r < 4; ++r) {
                const int m = m0 + wr + i * 16 + grp * 4 + r;
                C[(size_t)m * N + n] = f2bf(acc[i][j][r] + bv);
            }
        }
    }
}

// Flash attention, swapped-QK^T 32x32 + combined softmax + defer-max +
// async-STAGE + dbuf/1-barrier (r22). r23: STATIC-index V-write (the dynamic
// (j+a8)&7 extract was hidden VALU — rule #20); exp2 via builtin; Q arrives
// pre-scaled from the Q-projection (qscale folded into its epilogue).
__global__ __launch_bounds__(256) void attn_fwd(
    const bf16* __restrict__ Q, const bf16* __restrict__ K,
    const bf16* __restrict__ V, bf16* __restrict__ Y)
{
    constexpr int LDK = 72;
    constexpr int LDV = 72;
    constexpr int LDP = 40;
    __shared__ bf16 Kt[2 * 64 * LDK];      // double-buffered
    __shared__ bf16 Vt[2 * 64 * LDV];
    __shared__ bf16 Pt[4 * 32 * LDP];

    const int tid  = threadIdx.x;
    const int lane = tid & 63;
    const int wave = tid >> 6;
    const int l31  = lane & 31;
    const int hi   = lane >> 5;
    const int bh = blockIdx.y;
    const size_t base = (size_t)(bh >> 4) * NS * ND + (size_t)(bh & 15) * NHD;
    const int q0 = blockIdx.x * 128 + wave * 32;

    // Q fragments (already scaled by 1/sqrt(HD)*log2e in the Q-projection)
    bf16x8 qB[4];
    {
        const bf16* qp = Q + base + (size_t)(q0 + l31) * ND + hi * 8;
        #pragma unroll
        for (int c = 0; c < 4; ++c)
            qB[c] = *reinterpret_cast<const bf16x8*>(qp + c * 16);
    }

    float mrow = -INFINITY, lrow = 0.f;
    f32x16 yacc0 = {}, yacc1 = {};

    const int a8  = tid & 7;
    const int rk  = tid >> 3;            // K rows rk, rk+32
    const int e0  = a8 * 8;
    const int rp  = tid >> 3;            // V row-pair
    const int d0  = a8 * 8;

    bf16* const ptW = Pt + wave * 32 * LDP;

    bf16x8 kr0, kr1, vr0, vr1;

    // prologue: stage tile 0 into buffer 0
    kr0 = *reinterpret_cast<const bf16x8*>(K + base + (size_t)(rk) * ND + e0);
    kr1 = *reinterpret_cast<const bf16x8*>(K + base + (size_t)(rk + 32) * ND + e0);
    vr0 = *reinterpret_cast<const bf16x8*>(V + base + (size_t)(2 * rp) * ND + d0);
    vr1 = *reinterpret_cast<const bf16x8*>(V + base + (size_t)(2 * rp) * ND + ND + d0);
    {
        *reinterpret_cast<bf16x8*>(Kt + rk * LDK + e0) = kr0;
        *reinterpret_cast<bf16x8*>(Kt + (rk + 32) * LDK + e0) = kr1;
        #pragma unroll
        for (int j = 0; j < 8; ++j) {    // STATIC index: subreg refs + imm offsets
            bf16x2 pr = { vr0[j], vr1[j] };
            *reinterpret_cast<u32*>(Vt + (d0 + j) * LDV + 2 * rp) =
                __builtin_bit_cast(u32, pr);
        }
    }
    __syncthreads();

    for (int t = 0; t < NS / 64; ++t) {
        const int k0 = t * 64;
        const int B = t & 1;
        const bool more = (k0 + 64 < NS);
        const bf16* const KtB = Kt + B * 64 * LDK;
        const bf16* const VtB = Vt + B * 64 * LDV;

        if (more) {   // issue next tile's loads early (T14)
            kr0 = *reinterpret_cast<const bf16x8*>(K + base + (size_t)(k0 + 64 + rk) * ND + e0);
            kr1 = *reinterpret_cast<const bf16x8*>(K + base + (size_t)(k0 + 64 + rk + 32) * ND + e0);
            vr0 = *reinterpret_cast<const bf16x8*>(V + base + (size_t)(k0 + 64 + 2 * rp) * ND + d0);
            vr1 = *reinterpret_cast<const bf16x8*>(V + base + (size_t)(k0 + 64 + 2 * rp) * ND + ND + d0);
        }

        // ---- S for both subtiles ----
        f32x16 s0 = {}, s1 = {};
        #pragma unroll
        for (int c = 0; c < 4; ++c) {
            bf16x8 kf = *reinterpret_cast<const bf16x8*>(
                KtB + l31 * LDK + c * 16 + hi * 8);
            s0 = mfma32(kf, qB[c], s0);
        }
        #pragma unroll
        for (int c = 0; c < 4; ++c) {
            bf16x8 kf = *reinterpret_cast<const bf16x8*>(
                KtB + (32 + l31) * LDK + c * 16 + hi * 8);
            s1 = mfma32(kf, qB[c], s1);
        }

        // ---- combined softmax (tree reductions, builtin exp2) ----
        float mx[16];
        #pragma unroll
        for (int i = 0; i < 16; ++i) mx[i] = fmaxf(s0[i], s1[i]);
        #pragma unroll
        for (int off = 8; off >= 1; off >>= 1)
            #pragma unroll
            for (int i = 0; i < 8; ++i)
                if (i < off) mx[i] = fmaxf(mx[i], mx[i + off]);
        float rmax = fmaxf(mx[0], __shfl_xor(mx[0], 32));
        if (!__all(rmax <= mrow + 8.0f)) {       // defer-max: rare rescale
            const float mnew = fmaxf(mrow, rmax);
            const float corr = fexp2(mrow - mnew);
            lrow *= corr;
            #pragma unroll
            for (int i = 0; i < 16; ++i) { yacc0[i] *= corr; yacc1[i] *= corr; }
            mrow = mnew;
        }
        #pragma unroll
        for (int i = 0; i < 16; ++i) s0[i] = fexp2(s0[i] - mrow);
        #pragma unroll
        for (int i = 0; i < 16; ++i) s1[i] = fexp2(s1[i] - mrow);
        float ps[16];
        #pragma unroll
        for (int i = 0; i < 16; ++i) ps[i] = s0[i] + s1[i];
        #pragma unroll
        for (int off = 8; off >= 1; off >>= 1)
            #pragma unroll
            for (int i = 0; i < 8; ++i)
                if (i < off) ps[i] += ps[i + off];
        lrow += ps[0];

        // ---- subtile 0: P -> LDS, PV ----
        #pragma unroll
        for (int cp = 0; cp < 4; ++cp) {
            u32x2 pw = { pack2bf(s0[4 * cp + 0], s0[4 * cp + 1]),
                         pack2bf(s0[4 * cp + 2], s0[4 * cp + 3]) };
            *reinterpret_cast<u32x2*>(ptW + l31 * LDP + 8 * cp + 4 * hi) = pw;
        }
        #pragma unroll
        for (int kc = 0; kc < 2; ++kc) {
            bf16x8 pf = *reinterpret_cast<const bf16x8*>(
                ptW + l31 * LDP + kc * 16 + hi * 8);
            bf16x8 vf0 = *reinterpret_cast<const bf16x8*>(
                VtB + l31 * LDV + kc * 16 + hi * 8);
            bf16x8 vf1 = *reinterpret_cast<const bf16x8*>(
                VtB + (32 + l31) * LDV + kc * 16 + hi * 8);
            yacc0 = mfma32(vf0, pf, yacc0);
            yacc1 = mfma32(vf1, pf, yacc1);
        }
        // ---- subtile 1 ----
        #pragma unroll
        for (int cp = 0; cp < 4; ++cp) {
            u32x2 pw = { pack2bf(s1[4 * cp + 0], s1[4 * cp + 1]),
                         pack2bf(s1[4 * cp + 2], s1[4 * cp + 3]) };
            *reinterpret_cast<u32x2*>(ptW + l31 * LDP + 8 * cp + 4 * hi) = pw;
        }
        #pragma unroll
        for (int kc = 0; kc < 2; ++kc) {
            bf16x8 pf = *reinterpret_cast<const bf16x8*>(
                ptW + l31 * LDP + kc * 16 + hi * 8);
            bf16x8 vf0 = *reinterpret_cast<const bf16x8*>(
                VtB + l31 * LDV + 32 + kc * 16 + hi * 8);
            bf16x8 vf1 = *reinterpret_cast<const bf16x8*>(
                VtB + (32 + l31) * LDV + 32 + kc * 16 + hi * 8);
            yacc0 = mfma32(vf0, pf, yacc0);
            yacc1 = mfma32(vf1, pf, yacc1);
        }

        // write pre-loaded t+1 into the other buffer
        if (more) {
            bf16* const KtN = Kt + (B ^ 1) * 64 * LDK;
            bf16* const VtN = Vt + (B ^ 1) * 64 * LDV;
            *reinterpret_cast<bf16x8*>(KtN + rk * LDK + e0) = kr0;
            *reinterpret_cast<bf16x8*>(KtN + (rk + 32) * LDK + e0) = kr1;
            #pragma unroll
            for (int j = 0; j < 8; ++j) {
                bf16x2 pr = { vr0[j], vr1[j] };
                *reinterpret_cast<u32*>(VtN + (d0 + j) * LDV + 2 * rp) =
                    __builtin_bit_cast(u32, pr);
            }
        }
        __syncthreads();     // one barrier per tile
    }

    lrow += __shfl_xor(lrow, 32);
    const float inv = 1.f / lrow;
    bf16* yp = Y + base + (size_t)(q0 + l31) * ND;
    #pragma unroll
    for (int cp = 0; cp < 4; ++cp) {
        bf16x4 o0 = { f2bf(yacc0[4*cp+0] * inv), f2bf(yacc0[4*cp+1] * inv),
                      f2bf(yacc0[4*cp+2] * inv), f2bf(yacc0[4*cp+3] * inv) };
        bf16x4 o1 = { f2bf(yacc1[4*cp+0] * inv), f2bf(yacc1[4*cp+1] * inv),
                      f2bf(yacc1[4*cp+2] * inv), f2bf(yacc1[4*cp+3] * inv) };
        *reinterpret_cast<bf16x4*>(yp + 8 * cp + 4 * hi)      = o0;
        *reinterpret_cast<bf16x4*>(yp + 32 + 8 * cp + 4 * hi) = o1;
    }
}

extern "C" void kernel_launch(void* const* d_in, const int* in_sizes, int n_in,
                              void* d_out, int out_size, void* d_ws, size_t ws_size,
                              hipStream_t stream) {
    float* outF = (float*)d_out;   // OUTPUT IS FLOAT32

    int c4 = 0, cW = 0, cB = 0;
    for (int i = 0; i < n_in; ++i) {
        if (in_sizes[i] == NB * NS * ND) ++c4;
        else if (in_sizes[i] == ND * ND) ++cW;
        else if (in_sizes[i] == ND) ++cB;
    }
    if (c4 != 3 || cW != 4 || cB != 4) {
        write_marker_f<<<1, 1, 0, stream>>>(outF, 2.0f);
        return;
    }
    const size_t tsz = (size_t)NB * NS * ND;       // 4194304
    if (ws_size < 2 * tsz * sizeof(bf16)) {        // 16 MiB
        write_marker_f<<<1, 1, 0, stream>>>(outF, 1.0f);
        return;
    }

    const float* q  = (const float*)d_in[0];
    const float* k  = (const float*)d_in[1];
    const float* v  = (const float*)d_in[2];
    const float* Wq = (const float*)d_in[4];
    const float* bq = (const float*)d_in[5];
    const float* Wk = (const float*)d_in[6];
    const float* bk = (const float*)d_in[7];
    const float* Wv = (const float*)d_in[8];
    const float* bv = (const float*)d_in[9];
    const float* Wo = (const float*)d_in[10];
    const float* bo = (const float*)d_in[11];

    // Buffer choreography (race-checked, r21):
    //  cvt_all: qbf->D0, kbf->D1, weights->S1
    //  Qgemm:  A=D0, W=S1+0 -> Qb=S0 (pre-scaled by qscale)
    //  Kgemm:  A=D1, W=S1+1 -> Kb=D0
    //  Vgemm:  A=v fp32, W=S1+2 -> Vb=D1
    //  attn:   Q=S0, K=D0, V=D1 -> Y=S0 (in-place, disjoint slices)
    //  final:  A=S0, W=S1+3 -> outF
    bf16* S0 = (bf16*)d_ws;
    bf16* S1 = S0 + tsz;
    bf16* D0 = (bf16*)d_out;
    bf16* D1 = D0 + tsz;
    const size_t wsz = (size_t)ND * ND;

    const int M = NB * NS;
    dim3 gg(M / 128, ND / 64);
    const float qscale = 0.125f * 1.44269504f;     // 1/sqrt(64) * log2(e)

    const int tn8 = (int)(tsz / 8);
    const int wn8 = (int)(wsz / 8);
    cvt_all<<<(2 * tn8 + 4 * wn8) / 256, 256, 0, stream>>>(
        q, k, Wq, Wk, Wv, Wo, D0, D1, S1, tn8, wn8);
    gemm_bb<<<gg, 256, 0, stream>>>(D0, S1 + 0 * wsz, bq, S0, M, ND, ND, qscale);
    gemm_bb<<<gg, 256, 0, stream>>>(D1, S1 + 1 * wsz, bk, D0, M, ND, ND, 1.0f);
    gemm_fb<<<gg, 256, 0, stream>>>(v, S1 + 2 * wsz, bv, D1, M, ND, ND);
    attn_fwd<<<dim3(NS / 128, NB * NH), 256, 0, stream>>>(S0, D0, D1, S0);
    gemm_bb_f32<<<gg, 256, 0, stream>>>(S0, S1 + 3 * wsz, bo, outF, M, ND, ND);
}

// Round 24
// 141.493 us; speedup vs baseline: 1.5683x; 1.0893x over previous
//
#include <hip/hip_runtime.h>
#include <math.h>

// Shapes (fixed by the problem)
#define NB 2
#define NS 2048
#define ND 1024
#define NH 16
#define NHD 64

typedef __bf16 bf16;
typedef __attribute__((ext_vector_type(2))) __bf16 bf16x2;
typedef __attribute__((ext_vector_type(4))) __bf16 bf16x4;
typedef __attribute__((ext_vector_type(8))) __bf16 bf16x8;
typedef __attribute__((ext_vector_type(4))) float f32x4;
typedef __attribute__((ext_vector_type(16))) float f32x16;
typedef unsigned int u32;
typedef __attribute__((ext_vector_type(2))) unsigned int u32x2;
typedef __attribute__((ext_vector_type(4))) unsigned int u32x4;

__device__ __forceinline__ float bf2f(bf16 x) {
    unsigned int w = ((unsigned int)__builtin_bit_cast(unsigned short, x)) << 16;
    return __builtin_bit_cast(float, w);
}
__device__ __forceinline__ bf16 f2bf(float f) { return (bf16)f; }
__device__ __forceinline__ u32 pack2bf(float a, float b) {
    bf16x2 t = { (bf16)a, (bf16)b };
    return __builtin_bit_cast(u32, t);
}
__device__ __forceinline__ float fexp2(float x) { return __builtin_amdgcn_exp2f(x); }

__device__ __forceinline__ f32x4 mfma16(bf16x8 a, bf16x8 b, f32x4 c) {
    return __builtin_amdgcn_mfma_f32_16x16x32_bf16(a, b, c, 0, 0, 0);
}
__device__ __forceinline__ f32x16 mfma32(bf16x8 a, bf16x8 b, f32x16 c) {
    return __builtin_amdgcn_mfma_f32_32x32x16_bf16(a, b, c, 0, 0, 0);
}

__global__ void write_marker_f(float* out, float v) { out[0] = v; }

// Fused 4-weight fp32 -> bf16 (one launch; dst contiguous 4 x N*K).
__global__ __launch_bounds__(256) void cvt_w(
    const float* __restrict__ w0, const float* __restrict__ w1,
    const float* __restrict__ w2, const float* __restrict__ w3,
    bf16* __restrict__ wd, int wn8)
{
    const int i = blockIdx.x * 256 + threadIdx.x;
    const int t = i / wn8;                   // 0..3, block-uniform (wn8 % 256 == 0)
    const int j = i - t * wn8;
    const float* src = (t == 0) ? w0 : (t == 1) ? w1 : (t == 2) ? w2 : w3;
    const f32x4* s4 = reinterpret_cast<const f32x4*>(src) + 2 * (size_t)j;
    f32x4 a = s4[0], b = s4[1];
    u32x4 p = { pack2bf(a[0], a[1]), pack2bf(a[2], a[3]),
                pack2bf(b[0], b[1]), pack2bf(b[2], b[3]) };
    *reinterpret_cast<u32x4*>(wd + (size_t)t * (size_t)wn8 * 8 + 8 * (size_t)j) = p;
}

// FUSED QKV projection: grid.z in {0,1,2} selects (A, bias, C, oscale).
// A fp32 (reg-staged + native cvt), W bf16 (gload_lds), 128x64 tile, BK=64.
// z-th weight matrix lives at Wbase + z*N*K.
__global__ __launch_bounds__(256) void gemm_qkv(
    const float* __restrict__ A0, const float* __restrict__ A1,
    const float* __restrict__ A2, const bf16* __restrict__ Wbase,
    const float* __restrict__ b0, const float* __restrict__ b1,
    const float* __restrict__ b2,
    bf16* __restrict__ C0, bf16* __restrict__ C1, bf16* __restrict__ C2,
    int M, int N, int K, float qscale)
{
    __shared__ bf16 At[2 * 128 * 32];
    __shared__ bf16 Bt[2 * 64 * 32];

    const int z = blockIdx.z;
    const float* __restrict__ A    = (z == 0) ? A0 : (z == 1) ? A1 : A2;
    const float* __restrict__ bias = (z == 0) ? b0 : (z == 1) ? b1 : b2;
    bf16* __restrict__ C           = (z == 0) ? C0 : (z == 1) ? C1 : C2;
    const bf16* __restrict__ W     = Wbase + (size_t)z * N * K;
    const float oscale             = (z == 0) ? qscale : 1.0f;

    const int tid   = threadIdx.x;
    const int lane  = tid & 63;
    const int wave  = tid >> 6;
    const int row16 = lane & 15;
    const int grp   = lane >> 4;
    const int m0 = blockIdx.x * 128;
    const int n0 = blockIdx.y * 64;
    const int wr = (wave >> 1) * 64;
    const int wc = (wave & 1) * 32;

    f32x4 acc[4][2] = {};

    const int cB = wave * 64 + lane;
    const int rB = cB >> 2, kB = (cB & 3) * 8;

    for (int k0 = 0; k0 < K; k0 += 64) {
        #pragma unroll
        for (int h = 0; h < 2; ++h) {
            __builtin_amdgcn_global_load_lds(
                (const __attribute__((address_space(1))) void*)(W + (size_t)(n0 + rB) * K + k0 + h * 32 + kB),
                (__attribute__((address_space(3))) void*)(Bt + h * 2048 + wave * 512), 16, 0, 0);
            #pragma unroll
            for (int i = 0; i < 4; ++i) {
                const int c   = tid + 256 * i;
                const int r   = c >> 3;
                const int col = (c & 7) * 4;
                f32x4 va = *reinterpret_cast<const f32x4*>(A + (size_t)(m0 + r) * K + k0 + h * 32 + col);
                u32x2 pa = { pack2bf(va[0], va[1]), pack2bf(va[2], va[3]) };
                *reinterpret_cast<u32x2*>(At + h * 4096 + r * 32 + col) = pa;
            }
        }
        __syncthreads();

        #pragma unroll
        for (int h = 0; h < 2; ++h) {
            bf16x8 a[4], b[2];
            #pragma unroll
            for (int i = 0; i < 4; ++i)
                a[i] = *reinterpret_cast<const bf16x8*>(At + h * 4096 + (wr + i * 16 + row16) * 32 + grp * 8);
            #pragma unroll
            for (int j = 0; j < 2; ++j)
                b[j] = *reinterpret_cast<const bf16x8*>(Bt + h * 2048 + (wc + j * 16 + row16) * 32 + grp * 8);
            #pragma unroll
            for (int i = 0; i < 4; ++i)
                #pragma unroll
                for (int j = 0; j < 2; ++j)
                    acc[i][j] = mfma16(a[i], b[j], acc[i][j]);
        }
        __syncthreads();
    }

    #pragma unroll
    for (int j = 0; j < 2; ++j) {
        const int n = n0 + wc + j * 16 + row16;
        const float bv = bias[n];
        #pragma unroll
        for (int i = 0; i < 4; ++i) {
            #pragma unroll
            for (int r = 0; r < 4; ++r) {
                const int m = m0 + wr + i * 16 + grp * 4 + r;
                C[(size_t)m * N + n] = f2bf((acc[i][j][r] + bv) * oscale);
            }
        }
    }
}

// Final projection: A bf16, W bf16 (gload_lds), fp32 out. 128x64, BK=64.
__global__ __launch_bounds__(256) void gemm_bb_f32(
    const bf16* __restrict__ A, const bf16* __restrict__ W,
    const float* __restrict__ bias, float* __restrict__ C,
    int M, int N, int K)
{
    __shared__ bf16 At[2 * 128 * 32];
    __shared__ bf16 Bt[2 * 64 * 32];

    const int tid   = threadIdx.x;
    const int lane  = tid & 63;
    const int wave  = tid >> 6;
    const int row16 = lane & 15;
    const int grp   = lane >> 4;
    const int m0 = blockIdx.x * 128;
    const int n0 = blockIdx.y * 64;
    const int wr = (wave >> 1) * 64;
    const int wc = (wave & 1) * 32;

    f32x4 acc[4][2] = {};

    const int cA0 = wave * 64 + lane;
    const int cA1 = cA0 + 256;
    const int rA0 = cA0 >> 2, kA0 = (cA0 & 3) * 8;
    const int rA1 = cA1 >> 2, kA1 = (cA1 & 3) * 8;
    const int rB  = cA0 >> 2, kB  = (cA0 & 3) * 8;

    for (int k0 = 0; k0 < K; k0 += 64) {
        #pragma unroll
        for (int h = 0; h < 2; ++h) {
            __builtin_amdgcn_global_load_lds(
                (const __attribute__((address_space(1))) void*)(A + (size_t)(m0 + rA0) * K + k0 + h * 32 + kA0),
                (__attribute__((address_space(3))) void*)(At + h * 4096 + wave * 512), 16, 0, 0);
            __builtin_amdgcn_global_load_lds(
                (const __attribute__((address_space(1))) void*)(A + (size_t)(m0 + rA1) * K + k0 + h * 32 + kA1),
                (__attribute__((address_space(3))) void*)(At + h * 4096 + 2048 + wave * 512), 16, 0, 0);
            __builtin_amdgcn_global_load_lds(
                (const __attribute__((address_space(1))) void*)(W + (size_t)(n0 + rB) * K + k0 + h * 32 + kB),
                (__attribute__((address_space(3))) void*)(Bt + h * 2048 + wave * 512), 16, 0, 0);
        }
        __syncthreads();

        #pragma unroll
        for (int h = 0; h < 2; ++h) {
            bf16x8 a[4], b[2];
            #pragma unroll
            for (int i = 0; i < 4; ++i)
                a[i] = *reinterpret_cast<const bf16x8*>(At + h * 4096 + (wr + i * 16 + row16) * 32 + grp * 8);
            #pragma unroll
            for (int j = 0; j < 2; ++j)
                b[j] = *reinterpret_cast<const bf16x8*>(Bt + h * 2048 + (wc + j * 16 + row16) * 32 + grp * 8);
            #pragma unroll
            for (int i = 0; i < 4; ++i)
                #pragma unroll
                for (int j = 0; j < 2; ++j)
                    acc[i][j] = mfma16(a[i], b[j], acc[i][j]);
        }
        __syncthreads();
    }

    #pragma unroll
    for (int j = 0; j < 2; ++j) {
        const int n = n0 + wc + j * 16 + row16;
        const float bv = bias[n];
        #pragma unroll
        for (int i = 0; i < 4; ++i) {
            #pragma unroll
            for (int r = 0; r < 4; ++r) {
                const int m = m0 + wr + i * 16 + grp * 4 + r;
                C[(size_t)m * N + n] = acc[i][j][r] + bv;
            }
        }
    }
}

// Flash attention (r23 structure, unchanged: 72.5 us verified).
__global__ __launch_bounds__(256) void attn_fwd(
    const bf16* __restrict__ Q, const bf16* __restrict__ K,
    const bf16* __restrict__ V, bf16* __restrict__ Y)
{
    constexpr int LDK = 72;
    constexpr int LDV = 72;
    constexpr int LDP = 40;
    __shared__ bf16 Kt[2 * 64 * LDK];      // double-buffered
    __shared__ bf16 Vt[2 * 64 * LDV];
    __shared__ bf16 Pt[4 * 32 * LDP];

    const int tid  = threadIdx.x;
    const int lane = tid & 63;
    const int wave = tid >> 6;
    const int l31  = lane & 31;
    const int hi   = lane >> 5;
    const int bh = blockIdx.y;
    const size_t base = (size_t)(bh >> 4) * NS * ND + (size_t)(bh & 15) * NHD;
    const int q0 = blockIdx.x * 128 + wave * 32;

    // Q fragments (pre-scaled by 1/sqrt(HD)*log2e in the Q-projection)
    bf16x8 qB[4];
    {
        const bf16* qp = Q + base + (size_t)(q0 + l31) * ND + hi * 8;
        #pragma unroll
        for (int c = 0; c < 4; ++c)
            qB[c] = *reinterpret_cast<const bf16x8*>(qp + c * 16);
    }

    float mrow = -INFINITY, lrow = 0.f;
    f32x16 yacc0 = {}, yacc1 = {};

    const int a8  = tid & 7;
    const int rk  = tid >> 3;
    const int e0  = a8 * 8;
    const int rp  = tid >> 3;
    const int d0  = a8 * 8;

    bf16* const ptW = Pt + wave * 32 * LDP;

    bf16x8 kr0, kr1, vr0, vr1;

    kr0 = *reinterpret_cast<const bf16x8*>(K + base + (size_t)(rk) * ND + e0);
    kr1 = *reinterpret_cast<const bf16x8*>(K + base + (size_t)(rk + 32) * ND + e0);
    vr0 = *reinterpret_cast<const bf16x8*>(V + base + (size_t)(2 * rp) * ND + d0);
    vr1 = *reinterpret_cast<const bf16x8*>(V + base + (size_t)(2 * rp) * ND + ND + d0);
    {
        *reinterpret_cast<bf16x8*>(Kt + rk * LDK + e0) = kr0;
        *reinterpret_cast<bf16x8*>(Kt + (rk + 32) * LDK + e0) = kr1;
        #pragma unroll
        for (int j = 0; j < 8; ++j) {
            bf16x2 pr = { vr0[j], vr1[j] };
            *reinterpret_cast<u32*>(Vt + (d0 + j) * LDV + 2 * rp) =
                __builtin_bit_cast(u32, pr);
        }
    }
    __syncthreads();

    for (int t = 0; t < NS / 64; ++t) {
        const int k0 = t * 64;
        const int B = t & 1;
        const bool more = (k0 + 64 < NS);
        const bf16* const KtB = Kt + B * 64 * LDK;
        const bf16* const VtB = Vt + B * 64 * LDV;

        if (more) {   // T14: issue next tile's loads early
            kr0 = *reinterpret_cast<const bf16x8*>(K + base + (size_t)(k0 + 64 + rk) * ND + e0);
            kr1 = *reinterpret_cast<const bf16x8*>(K + base + (size_t)(k0 + 64 + rk + 32) * ND + e0);
            vr0 = *reinterpret_cast<const bf16x8*>(V + base + (size_t)(k0 + 64 + 2 * rp) * ND + d0);
            vr1 = *reinterpret_cast<const bf16x8*>(V + base + (size_t)(k0 + 64 + 2 * rp) * ND + ND + d0);
        }

        f32x16 s0 = {}, s1 = {};
        #pragma unroll
        for (int c = 0; c < 4; ++c) {
            bf16x8 kf = *reinterpret_cast<const bf16x8*>(
                KtB + l31 * LDK + c * 16 + hi * 8);
            s0 = mfma32(kf, qB[c], s0);
        }
        #pragma unroll
        for (int c = 0; c < 4; ++c) {
            bf16x8 kf = *reinterpret_cast<const bf16x8*>(
                KtB + (32 + l31) * LDK + c * 16 + hi * 8);
            s1 = mfma32(kf, qB[c], s1);
        }

        float mx[16];
        #pragma unroll
        for (int i = 0; i < 16; ++i) mx[i] = fmaxf(s0[i], s1[i]);
        #pragma unroll
        for (int off = 8; off >= 1; off >>= 1)
            #pragma unroll
            for (int i = 0; i < 8; ++i)
                if (i < off) mx[i] = fmaxf(mx[i], mx[i + off]);
        float rmax = fmaxf(mx[0], __shfl_xor(mx[0], 32));
        if (!__all(rmax <= mrow + 8.0f)) {       // defer-max
            const float mnew = fmaxf(mrow, rmax);
            const float corr = fexp2(mrow - mnew);
            lrow *= corr;
            #pragma unroll
            for (int i = 0; i < 16; ++i) { yacc0[i] *= corr; yacc1[i] *= corr; }
            mrow = mnew;
        }
        #pragma unroll
        for (int i = 0; i < 16; ++i) s0[i] = fexp2(s0[i] - mrow);
        #pragma unroll
        for (int i = 0; i < 16; ++i) s1[i] = fexp2(s1[i] - mrow);
        float ps[16];
        #pragma unroll
        for (int i = 0; i < 16; ++i) ps[i] = s0[i] + s1[i];
        #pragma unroll
        for (int off = 8; off >= 1; off >>= 1)
            #pragma unroll
            for (int i = 0; i < 8; ++i)
                if (i < off) ps[i] += ps[i + off];
        lrow += ps[0];

        #pragma unroll
        for (int cp = 0; cp < 4; ++cp) {
            u32x2 pw = { pack2bf(s0[4 * cp + 0], s0[4 * cp + 1]),
                         pack2bf(s0[4 * cp + 2], s0[4 * cp + 3]) };
            *reinterpret_cast<u32x2*>(ptW + l31 * LDP + 8 * cp + 4 * hi) = pw;
        }
        #pragma unroll
        for (int kc = 0; kc < 2; ++kc) {
            bf16x8 pf = *reinterpret_cast<const bf16x8*>(
                ptW + l31 * LDP + kc * 16 + hi * 8);
            bf16x8 vf0 = *reinterpret_cast<const bf16x8*>(
                VtB + l31 * LDV + kc * 16 + hi * 8);
            bf16x8 vf1 = *reinterpret_cast<const bf16x8*>(
                VtB + (32 + l31) * LDV + kc * 16 + hi * 8);
            yacc0 = mfma32(vf0, pf, yacc0);
            yacc1 = mfma32(vf1, pf, yacc1);
        }
        #pragma unroll
        for (int cp = 0; cp < 4; ++cp) {
            u32x2 pw = { pack2bf(s1[4 * cp + 0], s1[4 * cp + 1]),
                         pack2bf(s1[4 * cp + 2], s1[4 * cp + 3]) };
            *reinterpret_cast<u32x2*>(ptW + l31 * LDP + 8 * cp + 4 * hi) = pw;
        }
        #pragma unroll
        for (int kc = 0; kc < 2; ++kc) {
            bf16x8 pf = *reinterpret_cast<const bf16x8*>(
                ptW + l31 * LDP + kc * 16 + hi * 8);
            bf16x8 vf0 = *reinterpret_cast<const bf16x8*>(
                VtB + l31 * LDV + 32 + kc * 16 + hi * 8);
            bf16x8 vf1 = *reinterpret_cast<const bf16x8*>(
                VtB + (32 + l31) * LDV + 32 + kc * 16 + hi * 8);
            yacc0 = mfma32(vf0, pf, yacc0);
            yacc1 = mfma32(vf1, pf, yacc1);
        }

        if (more) {
            bf16* const KtN = Kt + (B ^ 1) * 64 * LDK;
            bf16* const VtN = Vt + (B ^ 1) * 64 * LDV;
            *reinterpret_cast<bf16x8*>(KtN + rk * LDK + e0) = kr0;
            *reinterpret_cast<bf16x8*>(KtN + (rk + 32) * LDK + e0) = kr1;
            #pragma unroll
            for (int j = 0; j < 8; ++j) {
                bf16x2 pr = { vr0[j], vr1[j] };
                *reinterpret_cast<u32*>(VtN + (d0 + j) * LDV + 2 * rp) =
                    __builtin_bit_cast(u32, pr);
            }
        }
        __syncthreads();
    }

    lrow += __shfl_xor(lrow, 32);
    const float inv = 1.f / lrow;
    bf16* yp = Y + base + (size_t)(q0 + l31) * ND;
    #pragma unroll
    for (int cp = 0; cp < 4; ++cp) {
        bf16x4 o0 = { f2bf(yacc0[4*cp+0] * inv), f2bf(yacc0[4*cp+1] * inv),
                      f2bf(yacc0[4*cp+2] * inv), f2bf(yacc0[4*cp+3] * inv) };
        bf16x4 o1 = { f2bf(yacc1[4*cp+0] * inv), f2bf(yacc1[4*cp+1] * inv),
                      f2bf(yacc1[4*cp+2] * inv), f2bf(yacc1[4*cp+3] * inv) };
        *reinterpret_cast<bf16x4*>(yp + 8 * cp + 4 * hi)      = o0;
        *reinterpret_cast<bf16x4*>(yp + 32 + 8 * cp + 4 * hi) = o1;
    }
}

extern "C" void kernel_launch(void* const* d_in, const int* in_sizes, int n_in,
                              void* d_out, int out_size, void* d_ws, size_t ws_size,
                              hipStream_t stream) {
    float* outF = (float*)d_out;   // OUTPUT IS FLOAT32

    int c4 = 0, cW = 0, cB = 0;
    for (int i = 0; i < n_in; ++i) {
        if (in_sizes[i] == NB * NS * ND) ++c4;
        else if (in_sizes[i] == ND * ND) ++cW;
        else if (in_sizes[i] == ND) ++cB;
    }
    if (c4 != 3 || cW != 4 || cB != 4) {
        write_marker_f<<<1, 1, 0, stream>>>(outF, 2.0f);
        return;
    }
    const size_t tsz = (size_t)NB * NS * ND;       // 4194304
    if (ws_size < 2 * tsz * sizeof(bf16)) {        // 16 MiB
        write_marker_f<<<1, 1, 0, stream>>>(outF, 1.0f);
        return;
    }

    const float* q  = (const float*)d_in[0];
    const float* k  = (const float*)d_in[1];
    const float* v  = (const float*)d_in[2];
    const float* Wq = (const float*)d_in[4];
    const float* bq = (const float*)d_in[5];
    const float* Wk = (const float*)d_in[6];
    const float* bk = (const float*)d_in[7];
    const float* Wv = (const float*)d_in[8];
    const float* bv = (const float*)d_in[9];
    const float* Wo = (const float*)d_in[10];
    const float* bo = (const float*)d_in[11];

    // Buffer choreography (race-checked):
    //  cvt_w:  Wq|Wk|Wv|Wo bf16 -> S1 (read-only afterwards)
    //  QKV fused (z=0,1,2): A = q|k|v fp32 inputs; C = S0|D0|D1
    //          (Q output pre-scaled by qscale)
    //  attn:   Q=S0, K=D0, V=D1 -> Y=S0 (in-place, disjoint slices)
    //  final:  A=S0, W=S1+3 -> outF (overwrites D0|D1; dead by then)
    bf16* S0 = (bf16*)d_ws;
    bf16* S1 = S0 + tsz;
    bf16* D0 = (bf16*)d_out;
    bf16* D1 = D0 + tsz;
    const size_t wsz = (size_t)ND * ND;

    const int M = NB * NS;
    const float qscale = 0.125f * 1.44269504f;     // 1/sqrt(64) * log2(e)
    const int wn8 = (int)(wsz / 8);

    cvt_w<<<4 * wn8 / 256, 256, 0, stream>>>(Wq, Wk, Wv, Wo, S1, wn8);
    gemm_qkv<<<dim3(M / 128, ND / 64, 3), 256, 0, stream>>>(
        q, k, v, S1, bq, bk, bv, S0, D0, D1, M, ND, ND, qscale);
    attn_fwd<<<dim3(NS / 128, NB * NH), 256, 0, stream>>>(S0, D0, D1, S0);
    gemm_bb_f32<<<dim3(M / 128, ND / 64), 256, 0, stream>>>(
        S0, S1 + 3 * wsz, bo, outF, M, ND, ND);
}

// Round 25
// 137.861 us; speedup vs baseline: 1.6096x; 1.0263x over previous
//
#include <hip/hip_runtime.h>
#include <math.h>

// Shapes (fixed by the problem)
#define NB 2
#define NS 2048
#define ND 1024
#define NH 16
#define NHD 64

typedef __bf16 bf16;
typedef __attribute__((ext_vector_type(2))) __bf16 bf16x2;
typedef __attribute__((ext_vector_type(4))) __bf16 bf16x4;
typedef __attribute__((ext_vector_type(8))) __bf16 bf16x8;
typedef __attribute__((ext_vector_type(4))) float f32x4;
typedef __attribute__((ext_vector_type(16))) float f32x16;
typedef unsigned int u32;
typedef __attribute__((ext_vector_type(2))) unsigned int u32x2;
typedef __attribute__((ext_vector_type(4))) unsigned int u32x4;

__device__ __forceinline__ float bf2f(bf16 x) {
    unsigned int w = ((unsigned int)__builtin_bit_cast(unsigned short, x)) << 16;
    return __builtin_bit_cast(float, w);
}
__device__ __forceinline__ bf16 f2bf(float f) { return (bf16)f; }
__device__ __forceinline__ u32 pack2bf(float a, float b) {
    bf16x2 t = { (bf16)a, (bf16)b };
    return __builtin_bit_cast(u32, t);
}
__device__ __forceinline__ float fexp2(float x) { return __builtin_amdgcn_exp2f(x); }

__device__ __forceinline__ f32x4 mfma16(bf16x8 a, bf16x8 b, f32x4 c) {
    return __builtin_amdgcn_mfma_f32_16x16x32_bf16(a, b, c, 0, 0, 0);
}
__device__ __forceinline__ f32x16 mfma32(bf16x8 a, bf16x8 b, f32x16 c) {
    return __builtin_amdgcn_mfma_f32_32x32x16_bf16(a, b, c, 0, 0, 0);
}

__global__ void write_marker_f(float* out, float v) { out[0] = v; }

// Fused 4-weight fp32 -> bf16 (one launch; dst contiguous 4 x N*K).
__global__ __launch_bounds__(256) void cvt_w(
    const float* __restrict__ w0, const float* __restrict__ w1,
    const float* __restrict__ w2, const float* __restrict__ w3,
    bf16* __restrict__ wd, int wn8)
{
    const int i = blockIdx.x * 256 + threadIdx.x;
    const int t = i / wn8;                   // 0..3, block-uniform
    const int j = i - t * wn8;
    const float* src = (t == 0) ? w0 : (t == 1) ? w1 : (t == 2) ? w2 : w3;
    const f32x4* s4 = reinterpret_cast<const f32x4*>(src) + 2 * (size_t)j;
    f32x4 a = s4[0], b = s4[1];
    u32x4 p = { pack2bf(a[0], a[1]), pack2bf(a[2], a[3]),
                pack2bf(b[0], b[1]), pack2bf(b[2], b[3]) };
    *reinterpret_cast<u32x4*>(wd + (size_t)t * (size_t)wn8 * 8 + 8 * (size_t)j) = p;
}

// FUSED QKV projection: grid.z selects (A, bias, C, oscale). (r24, unchanged)
__global__ __launch_bounds__(256) void gemm_qkv(
    const float* __restrict__ A0, const float* __restrict__ A1,
    const float* __restrict__ A2, const bf16* __restrict__ Wbase,
    const float* __restrict__ b0, const float* __restrict__ b1,
    const float* __restrict__ b2,
    bf16* __restrict__ C0, bf16* __restrict__ C1, bf16* __restrict__ C2,
    int M, int N, int K, float qscale)
{
    __shared__ bf16 At[2 * 128 * 32];
    __shared__ bf16 Bt[2 * 64 * 32];

    const int z = blockIdx.z;
    const float* __restrict__ A    = (z == 0) ? A0 : (z == 1) ? A1 : A2;
    const float* __restrict__ bias = (z == 0) ? b0 : (z == 1) ? b1 : b2;
    bf16* __restrict__ C           = (z == 0) ? C0 : (z == 1) ? C1 : C2;
    const bf16* __restrict__ W     = Wbase + (size_t)z * N * K;
    const float oscale             = (z == 0) ? qscale : 1.0f;

    const int tid   = threadIdx.x;
    const int lane  = tid & 63;
    const int wave  = tid >> 6;
    const int row16 = lane & 15;
    const int grp   = lane >> 4;
    const int m0 = blockIdx.x * 128;
    const int n0 = blockIdx.y * 64;
    const int wr = (wave >> 1) * 64;
    const int wc = (wave & 1) * 32;

    f32x4 acc[4][2] = {};

    const int cB = wave * 64 + lane;
    const int rB = cB >> 2, kB = (cB & 3) * 8;

    for (int k0 = 0; k0 < K; k0 += 64) {
        #pragma unroll
        for (int h = 0; h < 2; ++h) {
            __builtin_amdgcn_global_load_lds(
                (const __attribute__((address_space(1))) void*)(W + (size_t)(n0 + rB) * K + k0 + h * 32 + kB),
                (__attribute__((address_space(3))) void*)(Bt + h * 2048 + wave * 512), 16, 0, 0);
            #pragma unroll
            for (int i = 0; i < 4; ++i) {
                const int c   = tid + 256 * i;
                const int r   = c >> 3;
                const int col = (c & 7) * 4;
                f32x4 va = *reinterpret_cast<const f32x4*>(A + (size_t)(m0 + r) * K + k0 + h * 32 + col);
                u32x2 pa = { pack2bf(va[0], va[1]), pack2bf(va[2], va[3]) };
                *reinterpret_cast<u32x2*>(At + h * 4096 + r * 32 + col) = pa;
            }
        }
        __syncthreads();

        #pragma unroll
        for (int h = 0; h < 2; ++h) {
            bf16x8 a[4], b[2];
            #pragma unroll
            for (int i = 0; i < 4; ++i)
                a[i] = *reinterpret_cast<const bf16x8*>(At + h * 4096 + (wr + i * 16 + row16) * 32 + grp * 8);
            #pragma unroll
            for (int j = 0; j < 2; ++j)
                b[j] = *reinterpret_cast<const bf16x8*>(Bt + h * 2048 + (wc + j * 16 + row16) * 32 + grp * 8);
            #pragma unroll
            for (int i = 0; i < 4; ++i)
                #pragma unroll
                for (int j = 0; j < 2; ++j)
                    acc[i][j] = mfma16(a[i], b[j], acc[i][j]);
        }
        __syncthreads();
    }

    #pragma unroll
    for (int j = 0; j < 2; ++j) {
        const int n = n0 + wc + j * 16 + row16;
        const float bv = bias[n];
        #pragma unroll
        for (int i = 0; i < 4; ++i) {
            #pragma unroll
            for (int r = 0; r < 4; ++r) {
                const int m = m0 + wr + i * 16 + grp * 4 + r;
                C[(size_t)m * N + n] = f2bf((acc[i][j][r] + bv) * oscale);
            }
        }
    }
}

// Final projection: A bf16, W bf16 (gload_lds), fp32 out. (r24, unchanged)
__global__ __launch_bounds__(256) void gemm_bb_f32(
    const bf16* __restrict__ A, const bf16* __restrict__ W,
    const float* __restrict__ bias, float* __restrict__ C,
    int M, int N, int K)
{
    __shared__ bf16 At[2 * 128 * 32];
    __shared__ bf16 Bt[2 * 64 * 32];

    const int tid   = threadIdx.x;
    const int lane  = tid & 63;
    const int wave  = tid >> 6;
    const int row16 = lane & 15;
    const int grp   = lane >> 4;
    const int m0 = blockIdx.x * 128;
    const int n0 = blockIdx.y * 64;
    const int wr = (wave >> 1) * 64;
    const int wc = (wave & 1) * 32;

    f32x4 acc[4][2] = {};

    const int cA0 = wave * 64 + lane;
    const int cA1 = cA0 + 256;
    const int rA0 = cA0 >> 2, kA0 = (cA0 & 3) * 8;
    const int rA1 = cA1 >> 2, kA1 = (cA1 & 3) * 8;
    const int rB  = cA0 >> 2, kB  = (cA0 & 3) * 8;

    for (int k0 = 0; k0 < K; k0 += 64) {
        #pragma unroll
        for (int h = 0; h < 2; ++h) {
            __builtin_amdgcn_global_load_lds(
                (const __attribute__((address_space(1))) void*)(A + (size_t)(m0 + rA0) * K + k0 + h * 32 + kA0),
                (__attribute__((address_space(3))) void*)(At + h * 4096 + wave * 512), 16, 0, 0);
            __builtin_amdgcn_global_load_lds(
                (const __attribute__((address_space(1))) void*)(A + (size_t)(m0 + rA1) * K + k0 + h * 32 + kA1),
                (__attribute__((address_space(3))) void*)(At + h * 4096 + 2048 + wave * 512), 16, 0, 0);
            __builtin_amdgcn_global_load_lds(
                (const __attribute__((address_space(1))) void*)(W + (size_t)(n0 + rB) * K + k0 + h * 32 + kB),
                (__attribute__((address_space(3))) void*)(Bt + h * 2048 + wave * 512), 16, 0, 0);
        }
        __syncthreads();

        #pragma unroll
        for (int h = 0; h < 2; ++h) {
            bf16x8 a[4], b[2];
            #pragma unroll
            for (int i = 0; i < 4; ++i)
                a[i] = *reinterpret_cast<const bf16x8*>(At + h * 4096 + (wr + i * 16 + row16) * 32 + grp * 8);
            #pragma unroll
            for (int j = 0; j < 2; ++j)
                b[j] = *reinterpret_cast<const bf16x8*>(Bt + h * 2048 + (wc + j * 16 + row16) * 32 + grp * 8);
            #pragma unroll
            for (int i = 0; i < 4; ++i)
                #pragma unroll
                for (int j = 0; j < 2; ++j)
                    acc[i][j] = mfma16(a[i], b[j], acc[i][j]);
        }
        __syncthreads();
    }

    #pragma unroll
    for (int j = 0; j < 2; ++j) {
        const int n = n0 + wc + j * 16 + row16;
        const float bv = bias[n];
        #pragma unroll
        for (int i = 0; i < 4; ++i) {
            #pragma unroll
            for (int r = 0; r < 4; ++r) {
                const int m = m0 + wr + i * 16 + grp * 4 + r;
                C[(size_t)m * N + n] = acc[i][j][r] + bv;
            }
        }
    }
}

// Flash attention with INTRA-BLOCK SPLIT-KV: 8 waves, waves 0-3 = k-half 0,
// waves 4-7 = k-half 1, same 128 q-rows. Per-group single-buffered K/V LDS
// (T14 reg-prefetch, 2 barriers/tile); per-wave swapped-QK^T 32x32 softmax
// (r23 body). End: partner waves merge (m,l,Y) through LDS overlaid on the
// dead K/V region. LDS 56KB -> 2 blocks/CU -> 16 waves/CU (2x r24).
__global__ __launch_bounds__(512, 4) void attn_fwd(
    const bf16* __restrict__ Q, const bf16* __restrict__ K,
    const bf16* __restrict__ V, bf16* __restrict__ Y)
{
    constexpr int LDK = 72;
    constexpr int LDV = 72;
    constexpr int LDP = 40;
    constexpr int LDC = 65;                 // combine rows (f32), conflict-free
    // 57344 B: Kt[2][64][72] | Vt[2][64][72] | Pt[8][32][40]
    __shared__ __align__(16) char smem[57344];
    bf16* const Kt = (bf16*)smem;                    // 18432 B
    bf16* const Vt = (bf16*)(smem + 18432);          // 18432 B
    bf16* const Pt = (bf16*)(smem + 36864);          // 20480 B
    // combine overlays (dead regions at merge time):
    float* const Cy = (float*)smem;                  // [4][32][65] f32 = 33280 B
    float* const Cm = (float*)(smem + 36864);        // [4][32]
    float* const Cl = (float*)(smem + 36864 + 512);  // [4][32]

    const int tid  = threadIdx.x;
    const int lane = tid & 63;
    const int wave = tid >> 6;          // 0..7
    const int gK   = wave >> 2;         // k-half group
    const int w4   = wave & 3;          // q-subtile
    const int l31  = lane & 31;
    const int hi   = lane >> 5;
    const int bh = blockIdx.y;
    const size_t base = (size_t)(bh >> 4) * NS * ND + (size_t)(bh & 15) * NHD;
    const int q0 = blockIdx.x * 128 + w4 * 32;
    const int kbase = gK * (NS / 2);

    // Q fragments (pre-scaled by 1/sqrt(HD)*log2e in the Q-projection)
    bf16x8 qB[4];
    {
        const bf16* qp = Q + base + (size_t)(q0 + l31) * ND + hi * 8;
        #pragma unroll
        for (int c = 0; c < 4; ++c)
            qB[c] = *reinterpret_cast<const bf16x8*>(qp + c * 16);
    }

    float mrow = -INFINITY, lrow = 0.f;
    f32x16 yacc0 = {}, yacc1 = {};

    // group-local staging indices (256 threads per group)
    const int t256 = tid & 255;
    const int a8   = t256 & 7;
    const int rk   = t256 >> 3;         // 0..31 (K rows rk, rk+32; V pair 2rk)
    const int e0   = a8 * 8;

    bf16* const KtG = Kt + gK * 64 * LDK;
    bf16* const VtG = Vt + gK * 64 * LDV;
    bf16* const ptW = Pt + wave * 32 * LDP;

    bf16x8 kr0, kr1, vr0, vr1;

    // prologue: stage this group's tile 0
    kr0 = *reinterpret_cast<const bf16x8*>(K + base + (size_t)(kbase + rk) * ND + e0);
    kr1 = *reinterpret_cast<const bf16x8*>(K + base + (size_t)(kbase + rk + 32) * ND + e0);
    vr0 = *reinterpret_cast<const bf16x8*>(V + base + (size_t)(kbase + 2 * rk) * ND + e0);
    vr1 = *reinterpret_cast<const bf16x8*>(V + base + (size_t)(kbase + 2 * rk) * ND + ND + e0);
    {
        *reinterpret_cast<bf16x8*>(KtG + rk * LDK + e0) = kr0;
        *reinterpret_cast<bf16x8*>(KtG + (rk + 32) * LDK + e0) = kr1;
        #pragma unroll
        for (int j = 0; j < 8; ++j) {
            bf16x2 pr = { vr0[j], vr1[j] };
            *reinterpret_cast<u32*>(VtG + (e0 + j) * LDV + 2 * rk) =
                __builtin_bit_cast(u32, pr);
        }
    }
    __syncthreads();

    for (int t = 0; t < NS / 128; ++t) {     // 16 tiles per group
        const int k0 = kbase + t * 64;
        const bool more = (t + 1 < NS / 128);

        if (more) {   // T14: issue next tile's loads early
            kr0 = *reinterpret_cast<const bf16x8*>(K + base + (size_t)(k0 + 64 + rk) * ND + e0);
            kr1 = *reinterpret_cast<const bf16x8*>(K + base + (size_t)(k0 + 64 + rk + 32) * ND + e0);
            vr0 = *reinterpret_cast<const bf16x8*>(V + base + (size_t)(k0 + 64 + 2 * rk) * ND + e0);
            vr1 = *reinterpret_cast<const bf16x8*>(V + base + (size_t)(k0 + 64 + 2 * rk) * ND + ND + e0);
        }

        // ---- S for both subtiles ----
        f32x16 s0 = {}, s1 = {};
        #pragma unroll
        for (int c = 0; c < 4; ++c) {
            bf16x8 kf = *reinterpret_cast<const bf16x8*>(
                KtG + l31 * LDK + c * 16 + hi * 8);
            s0 = mfma32(kf, qB[c], s0);
        }
        #pragma unroll
        for (int c = 0; c < 4; ++c) {
            bf16x8 kf = *reinterpret_cast<const bf16x8*>(
                KtG + (32 + l31) * LDK + c * 16 + hi * 8);
            s1 = mfma32(kf, qB[c], s1);
        }

        // ---- combined softmax (tree reductions) ----
        float mx[16];
        #pragma unroll
        for (int i = 0; i < 16; ++i) mx[i] = fmaxf(s0[i], s1[i]);
        #pragma unroll
        for (int off = 8; off >= 1; off >>= 1)
            #pragma unroll
            for (int i = 0; i < 8; ++i)
                if (i < off) mx[i] = fmaxf(mx[i], mx[i + off]);
        float rmax = fmaxf(mx[0], __shfl_xor(mx[0], 32));
        if (!__all(rmax <= mrow + 8.0f)) {       // defer-max
            const float mnew = fmaxf(mrow, rmax);
            const float corr = fexp2(mrow - mnew);
            lrow *= corr;
            #pragma unroll
            for (int i = 0; i < 16; ++i) { yacc0[i] *= corr; yacc1[i] *= corr; }
            mrow = mnew;
        }
        #pragma unroll
        for (int i = 0; i < 16; ++i) s0[i] = fexp2(s0[i] - mrow);
        #pragma unroll
        for (int i = 0; i < 16; ++i) s1[i] = fexp2(s1[i] - mrow);
        float ps[16];
        #pragma unroll
        for (int i = 0; i < 16; ++i) ps[i] = s0[i] + s1[i];
        #pragma unroll
        for (int off = 8; off >= 1; off >>= 1)
            #pragma unroll
            for (int i = 0; i < 8; ++i)
                if (i < off) ps[i] += ps[i + off];
        lrow += ps[0];

        // ---- subtile 0: P -> LDS, PV ----
        #pragma unroll
        for (int cp = 0; cp < 4; ++cp) {
            u32x2 pw = { pack2bf(s0[4 * cp + 0], s0[4 * cp + 1]),
                         pack2bf(s0[4 * cp + 2], s0[4 * cp + 3]) };
            *reinterpret_cast<u32x2*>(ptW + l31 * LDP + 8 * cp + 4 * hi) = pw;
        }
        #pragma unroll
        for (int kc = 0; kc < 2; ++kc) {
            bf16x8 pf = *reinterpret_cast<const bf16x8*>(
                ptW + l31 * LDP + kc * 16 + hi * 8);
            bf16x8 vf0 = *reinterpret_cast<const bf16x8*>(
                VtG + l31 * LDV + kc * 16 + hi * 8);
            bf16x8 vf1 = *reinterpret_cast<const bf16x8*>(
                VtG + (32 + l31) * LDV + kc * 16 + hi * 8);
            yacc0 = mfma32(vf0, pf, yacc0);
            yacc1 = mfma32(vf1, pf, yacc1);
        }
        // ---- subtile 1 ----
        #pragma unroll
        for (int cp = 0; cp < 4; ++cp) {
            u32x2 pw = { pack2bf(s1[4 * cp + 0], s1[4 * cp + 1]),
                         pack2bf(s1[4 * cp + 2], s1[4 * cp + 3]) };
            *reinterpret_cast<u32x2*>(ptW + l31 * LDP + 8 * cp + 4 * hi) = pw;
        }
        #pragma unroll
        for (int kc = 0; kc < 2; ++kc) {
            bf16x8 pf = *reinterpret_cast<const bf16x8*>(
                ptW + l31 * LDP + kc * 16 + hi * 8);
            bf16x8 vf0 = *reinterpret_cast<const bf16x8*>(
                VtG + l31 * LDV + 32 + kc * 16 + hi * 8);
            bf16x8 vf1 = *reinterpret_cast<const bf16x8*>(
                VtG + (32 + l31) * LDV + 32 + kc * 16 + hi * 8);
            yacc0 = mfma32(vf0, pf, yacc0);
            yacc1 = mfma32(vf1, pf, yacc1);
        }

        __syncthreads();                 // all waves done reading their tiles
        if (more) {                      // write pre-loaded t+1 (data arrived)
            *reinterpret_cast<bf16x8*>(KtG + rk * LDK + e0) = kr0;
            *reinterpret_cast<bf16x8*>(KtG + (rk + 32) * LDK + e0) = kr1;
            #pragma unroll
            for (int j = 0; j < 8; ++j) {
                bf16x2 pr = { vr0[j], vr1[j] };
                *reinterpret_cast<u32*>(VtG + (e0 + j) * LDV + 2 * rk) =
                    __builtin_bit_cast(u32, pr);
            }
        }
        __syncthreads();
    }

    // finalize per-group l (combine hi halves)
    lrow += __shfl_xor(lrow, 32);

    // ---- merge the two k-half partials (pair = w4) ----
    __syncthreads();                     // K/V/P LDS now dead -> overlay
    if (gK == 1) {
        float* const cy = Cy + w4 * 32 * LDC;
        #pragma unroll
        for (int cp = 0; cp < 4; ++cp) {
            #pragma unroll
            for (int r = 0; r < 4; ++r) {
                const int d = r + 8 * cp + 4 * hi;
                cy[l31 * LDC + d]      = yacc0[4 * cp + r];
                cy[l31 * LDC + 32 + d] = yacc1[4 * cp + r];
            }
        }
        if (hi == 0) {
            Cm[w4 * 32 + l31] = mrow;
            Cl[w4 * 32 + l31] = lrow;
        }
    }
    __syncthreads();
    if (gK == 0) {
        const float* const cy = Cy + w4 * 32 * LDC;
        const float m1 = Cm[w4 * 32 + l31];
        const float l1 = Cl[w4 * 32 + l31];
        const float m  = fmaxf(mrow, m1);
        const float c0 = fexp2(mrow - m);
        const float c1 = fexp2(m1 - m);
        const float inv = 1.f / (lrow * c0 + l1 * c1);
        bf16* yp = Y + base + (size_t)(q0 + l31) * ND;
        #pragma unroll
        for (int cp = 0; cp < 4; ++cp) {
            bf16x4 o0, o1;
            #pragma unroll
            for (int r = 0; r < 4; ++r) {
                const int d = r + 8 * cp + 4 * hi;
                const float y0 = yacc0[4 * cp + r] * c0 + cy[l31 * LDC + d] * c1;
                const float y1 = yacc1[4 * cp + r] * c0 + cy[l31 * LDC + 32 + d] * c1;
                o0[r] = f2bf(y0 * inv);
                o1[r] = f2bf(y1 * inv);
            }
            *reinterpret_cast<bf16x4*>(yp + 8 * cp + 4 * hi)      = o0;
            *reinterpret_cast<bf16x4*>(yp + 32 + 8 * cp + 4 * hi) = o1;
        }
    }
}

extern "C" void kernel_launch(void* const* d_in, const int* in_sizes, int n_in,
                              void* d_out, int out_size, void* d_ws, size_t ws_size,
                              hipStream_t stream) {
    float* outF = (float*)d_out;   // OUTPUT IS FLOAT32

    int c4 = 0, cW = 0, cB = 0;
    for (int i = 0; i < n_in; ++i) {
        if (in_sizes[i] == NB * NS * ND) ++c4;
        else if (in_sizes[i] == ND * ND) ++cW;
        else if (in_sizes[i] == ND) ++cB;
    }
    if (c4 != 3 || cW != 4 || cB != 4) {
        write_marker_f<<<1, 1, 0, stream>>>(outF, 2.0f);
        return;
    }
    const size_t tsz = (size_t)NB * NS * ND;       // 4194304
    if (ws_size < 2 * tsz * sizeof(bf16)) {        // 16 MiB
        write_marker_f<<<1, 1, 0, stream>>>(outF, 1.0f);
        return;
    }

    const float* q  = (const float*)d_in[0];
    const float* k  = (const float*)d_in[1];
    const float* v  = (const float*)d_in[2];
    const float* Wq = (const float*)d_in[4];
    const float* bq = (const float*)d_in[5];
    const float* Wk = (const float*)d_in[6];
    const float* bk = (const float*)d_in[7];
    const float* Wv = (const float*)d_in[8];
    const float* bv = (const float*)d_in[9];
    const float* Wo = (const float*)d_in[10];
    const float* bo = (const float*)d_in[11];

    // Buffer choreography (race-checked, r24):
    //  cvt_w:  Wq|Wk|Wv|Wo bf16 -> S1
    //  QKV fused (z=0,1,2): C = S0|D0|D1 (Q pre-scaled by qscale)
    //  attn:   Q=S0, K=D0, V=D1 -> Y=S0 (in-place, disjoint slices)
    //  final:  A=S0, W=S1+3 -> outF
    bf16* S0 = (bf16*)d_ws;
    bf16* S1 = S0 + tsz;
    bf16* D0 = (bf16*)d_out;
    bf16* D1 = D0 + tsz;
    const size_t wsz = (size_t)ND * ND;

    const int M = NB * NS;
    const float qscale = 0.125f * 1.44269504f;     // 1/sqrt(64) * log2(e)
    const int wn8 = (int)(wsz / 8);

    cvt_w<<<4 * wn8 / 256, 256, 0, stream>>>(Wq, Wk, Wv, Wo, S1, wn8);
    gemm_qkv<<<dim3(M / 128, ND / 64, 3), 256, 0, stream>>>(
        q, k, v, S1, bq, bk, bv, S0, D0, D1, M, ND, ND, qscale);
    attn_fwd<<<dim3(NS / 128, NB * NH), 512, 0, stream>>>(S0, D0, D1, S0);
    gemm_bb_f32<<<dim3(M / 128, ND / 64), 256, 0, stream>>>(
        S0, S1 + 3 * wsz, bo, outF, M, ND, ND);
}